// Round 14
// baseline (322.140 us; speedup 1.0000x reference)
//
#include <hip/hip_runtime.h>

typedef unsigned short u16;
typedef unsigned int u32;
typedef __attribute__((ext_vector_type(8))) short bf16x8;
typedef __attribute__((ext_vector_type(4))) float f32x4;

// Problem constants (fixed shapes from setup_inputs)
#define HS   48
#define WSB  48
#define NPIX 2304        // 48*48
#define CCH  128         // c
#define NT   6           // n*t
#define CIN  258         // 2c+2
#define HH   192
#define WW   192
#define PW   194         // padded img width/height

// ---- fallback ws layout (R8/R13, 49.3 MB) ----
#define EXTRA_OFF  0ull
#define OUTIMG_OFF 0ull
#define XA_OFF     4718592ull
#define XB_OFF     6488064ull
#define OFFS_OFF   8257536ull
#define ARAW_OFF   8699904ull
#define WT_OFF     8921088ull
#define SPT_OFF    4718592ull
#define ATTNW_OFF  11796480ull
#define SIDX_OFF   12017664ull
#define WBF_OFF    12238848ull

// ---- big ws layout (fused spprep + padded img, 90.4 MB) ----
#define SPT2_OFF    0ull           // bf16 [6nt][2304][2048] = 14,155,776 f32
#define EXTRA2_OFF  14155776ull    // extra (dead after conv1x1_l0)
#define IMGP_OFF    14155776ull    // bf16 [2][194][194][128] = 4,817,408 f32; overlaps dead extra+xa-head
#define XA2_OFF     17722368ull
#define XB2_OFF     19491840ull    // imgP ends 18,973,184 < XB2 ok
#define OFFS2_OFF   21261312ull
#define ARAW2_OFF   21703680ull
#define WT2_OFF     21924864ull
#define ATTNW2_OFF  22072320ull
#define SIDX2_OFF   22293504ull
#define WBF2_OFF    22514688ull
#define TOTAL2_F32  22588416ull    // 90,353,664 bytes

static __device__ __forceinline__ float leaky_f(float v) { return v >= 0.f ? v : 0.1f * v; }
static __device__ __forceinline__ u16 f2bf(float f) {
    u32 u = __float_as_uint(f);
    u = (u + 0x7fffu + ((u >> 16) & 1u)) >> 16;
    return (u16)u;
}
static __device__ __forceinline__ float bf2f(u16 v) {
    u32 u = ((u32)v) << 16;
    return __uint_as_float(u);
}

// ---- K0: pack fusion weights to bf16, phase-slab layout ----
__global__ __launch_bounds__(256) void k_wprep(const float* __restrict__ fw, u16* __restrict__ wbf) {
    int i = blockIdx.x * 256 + threadIdx.x;
    int j  = i & 7;
    int g  = (i >> 3) & 3;
    int oc = (i >> 5) & 127;
    int kcd = i >> 12;
    int d = kcd >> 2, kc = kcd & 3;
    int ic = kc * 32 + g * 8 + j;
    wbf[i] = f2bf(fw[((size_t)oc * 128 + ic) * 9 + d]);
}

// ---- K0b: transpose 3x3 net weights to wT[layer][net][ic][tap][oc] (f32) ----
__global__ __launch_bounds__(256) void k_wprep2(const float* __restrict__ so_w1, const float* __restrict__ aw_w1,
                                                const float* __restrict__ so_w2, const float* __restrict__ aw_w2,
                                                float* __restrict__ wT) {
    int i = blockIdx.x * 256 + threadIdx.x;
    int l   = i / 73728;
    int r1  = i % 73728;
    int net = r1 / 36864;
    int r   = r1 % 36864;
    int ic  = r / 576;
    int t2  = r % 576;
    int tap = t2 >> 6, oc = t2 & 63;
    const float* src = l ? (net ? aw_w2 : so_w2) : (net ? aw_w1 : so_w1);
    wT[i] = src[(size_t)oc * 576 + ic * 9 + tap];
}

// ---- K1 (fallback): avgpool ----
__global__ __launch_bounds__(256) void k_avgpool(const float* __restrict__ sp,
                                                 float* __restrict__ extra) {
    int idx = blockIdx.x * 256 + threadIdx.x;
    if (idx >= NT * CCH * NPIX) return;
    int pix = idx % NPIX;
    int cc  = (idx / NPIX) % CCH;
    int nt  = idx / (NPIX * CCH);
    const float* p = sp + ((size_t)nt * 2048 + (size_t)cc * 16) * NPIX + pix;
    float s = 0.f;
#pragma unroll
    for (int k = 0; k < 16; k++) s += p[(size_t)k * NPIX];
    extra[((size_t)nt * CIN + cc) * NPIX + pix] = s * 0.0625f;
}

// ---- K1b (big): fused transpose + avgpool ----
__global__ __launch_bounds__(256) void k_spprep(const float* __restrict__ sp,
                                                u16* __restrict__ spT2,
                                                float* __restrict__ extra) {
    __shared__ float tile[64][65];
    int tid = threadIdx.x;
    int pix0 = blockIdx.x * 64;
    int ch0  = blockIdx.y * 64;
    int nt   = blockIdx.z;
    const float* base = sp + ((size_t)nt * 2048 + ch0) * NPIX + pix0;
#pragma unroll
    for (int k = 0; k < 16; k++) {
        int row = k * 4 + (tid >> 6);
        int col = tid & 63;
        tile[row][col] = base[(size_t)row * NPIX + col];
    }
    __syncthreads();
#pragma unroll
    for (int k = 0; k < 2; k++) {
        int task = k * 256 + tid;
        int pl = task >> 3;
        int c0 = (task & 7) * 8;
        u16 pk[8];
#pragma unroll
        for (int j = 0; j < 8; j++) pk[j] = f2bf(tile[c0 + j][pl]);
        *reinterpret_cast<int4*>(spT2 + ((size_t)nt * NPIX + pix0 + pl) * 2048 + ch0 + c0) =
            *reinterpret_cast<const int4*>(pk);
    }
    {
        int ccl = tid >> 6;
        int col = tid & 63;
        float s = 0.f;
#pragma unroll
        for (int k = 0; k < 16; k++) s += tile[ccl * 16 + k][col];
        int cc = (ch0 >> 4) + ccl;
        extra[((size_t)nt * CIN + cc) * NPIX + pix0 + col] = s * 0.0625f;
    }
}

// ---- K2: extra rest ----
__global__ __launch_bounds__(256) void k_extra_rest(const float* __restrict__ flow,
                                                    float* __restrict__ extra) {
    int idx = blockIdx.x * 256 + threadIdx.x;
    if (idx >= NT * 130 * NPIX) return;
    int pix = idx % NPIX;
    int cc  = (idx / NPIX) % 130;
    int nt  = idx / (NPIX * 130);
    float fx = flow[((size_t)nt * 2 + 0) * NPIX + pix];
    float fy = flow[((size_t)nt * 2 + 1) * NPIX + pix];
    if (cc >= 128) {
        extra[((size_t)nt * CIN + 256 + (cc - 128)) * NPIX + pix] = (cc == 128) ? fx : fy;
        return;
    }
    int x = pix % WSB, y = pix / WSB;
    float locx = fx + (float)x;
    float locy = fy + (float)y;
    float gfx = 2.0f * locx / 47.0f - 1.0f;
    float gfy = 2.0f * locy / 47.0f - 1.0f;
    float rx = rintf(((gfx + 1.0f) * 0.5f) * 47.0f);
    float ry = rintf(((gfy + 1.0f) * 0.5f) * 47.0f);
    bool valid = (rx >= 0.f) && (rx <= 47.f) && (ry >= 0.f) && (ry <= 47.f);
    int sx = (int)fminf(fmaxf(rx, 0.f), 47.f);
    int sy = (int)fminf(fmaxf(ry, 0.f), 47.f);
    float v = valid ? extra[((size_t)nt * CIN + cc) * NPIX + sy * WSB + sx] : 0.f;
    extra[((size_t)nt * CIN + 128 + cc) * NPIX + pix] = v;
}

// ---- K3: 1x1 conv 258->64 + leaky ----
__global__ __launch_bounds__(256) void k_conv1x1_l0(const float* __restrict__ extra,
                                                    const float* __restrict__ w_so, const float* __restrict__ b_so,
                                                    const float* __restrict__ w_aw, const float* __restrict__ b_aw,
                                                    float* __restrict__ xa) {
    __shared__ float ws_[16 * CIN];
    int tile = blockIdx.x;
    int nt   = blockIdx.y;
    int z    = blockIdx.z;
    int net = z >> 2, ocg = z & 3;
    const float* wsel = net ? w_aw : w_so;
    const float* bsel = net ? b_aw : b_so;
    for (int i = threadIdx.x; i < 16 * CIN; i += 256)
        ws_[i] = wsel[(size_t)(ocg * 16) * CIN + i];
    __syncthreads();
    int pix = tile * 256 + threadIdx.x;
    float acc[16];
#pragma unroll
    for (int o = 0; o < 16; o++) acc[o] = bsel[ocg * 16 + o];
    const float* in = extra + (size_t)nt * CIN * NPIX + pix;
    for (int ci = 0; ci < CIN; ci++) {
        float v = in[(size_t)ci * NPIX];
#pragma unroll
        for (int o = 0; o < 16; o++) acc[o] = fmaf(ws_[o * CIN + ci], v, acc[o]);
    }
    float* op = xa + (((size_t)net * NT + nt) * 64 + ocg * 16) * NPIX + pix;
#pragma unroll
    for (int o = 0; o < 16; o++) op[(size_t)o * NPIX] = leaky_f(acc[o]);
}

// ---- K4 (R8): 3x3 conv 64->64 pad1 + leaky, register-tile fp32 ----
__global__ __launch_bounds__(256) void k_conv3x3(const float* __restrict__ xin,
                                                 const float* __restrict__ wT,
                                                 const float* __restrict__ b_so, const float* __restrict__ b_aw,
                                                 float* __restrict__ xout) {
    __shared__ float At[16][6][24];
    __shared__ float Bt[16][9][64];
    int tid = threadIdx.x;
    int txq = tid & 3, tyq = (tid >> 2) & 3, ocg = tid >> 4;
    int st = blockIdx.x;
    int x0 = (st % 3) * 16, y0 = (st / 3) * 4;
    int nt = blockIdx.y, net = blockIdx.z;
    const float* in  = xin + ((size_t)net * NT + nt) * 64 * NPIX;
    const float* wTn = wT + (size_t)net * 36864;
    const float* bsel = net ? b_aw : b_so;

    float acc[4][4];
#pragma unroll
    for (int o = 0; o < 4; o++) {
        float bv = bsel[ocg * 4 + o];
#pragma unroll
        for (int p = 0; p < 4; p++) acc[o][p] = bv;
    }

    for (int c0 = 0; c0 < 64; c0 += 16) {
        __syncthreads();
        for (int i = tid; i < 1728; i += 256) {
            int ic = i / 108, r = i % 108;
            int ry = r / 18, rx = r % 18;
            int gy = y0 + ry - 1, gx = x0 + rx - 1;
            float v = 0.f;
            if (gy >= 0 && gy < HS && gx >= 0 && gx < WSB)
                v = in[(size_t)(c0 + ic) * NPIX + gy * WSB + gx];
            At[ic][ry][rx] = v;
        }
        {
            const float* src = wTn + (size_t)c0 * 576;
            float* dst = &Bt[0][0][0];
            for (int i = tid; i < 9216; i += 256) dst[i] = src[i];
        }
        __syncthreads();
#pragma unroll 2
        for (int ic = 0; ic < 16; ic++) {
#pragma unroll
            for (int dy = 0; dy < 3; dy++) {
                f32x4 a0 = *reinterpret_cast<const f32x4*>(&At[ic][tyq + dy][4 * txq]);
                f32x4 a1 = *reinterpret_cast<const f32x4*>(&At[ic][tyq + dy][4 * txq + 4]);
#pragma unroll
                for (int dx = 0; dx < 3; dx++) {
                    f32x4 bv = *reinterpret_cast<const f32x4*>(&Bt[ic][dy * 3 + dx][4 * ocg]);
#pragma unroll
                    for (int p = 0; p < 4; p++) {
                        float av = (dx + p < 4) ? a0[dx + p] : a1[dx + p - 4];
#pragma unroll
                        for (int o = 0; o < 4; o++)
                            acc[o][p] = fmaf(bv[o], av, acc[o][p]);
                    }
                }
            }
        }
    }

    int py = y0 + tyq, pxb = x0 + 4 * txq;
#pragma unroll
    for (int o = 0; o < 4; o++) {
        f32x4 res;
#pragma unroll
        for (int p = 0; p < 4; p++) res[p] = leaky_f(acc[o][p]);
        float* op = xout + (((size_t)net * NT + nt) * 64 + ocg * 4 + o) * NPIX + py * WSB + pxb;
        *reinterpret_cast<f32x4*>(op) = res;
    }
}

// ---- K5: final 1x1 convs ----
__global__ __launch_bounds__(256) void k_conv1x1_l3(const float* __restrict__ xin,
                                                    const float* __restrict__ w_so, const float* __restrict__ b_so,
                                                    const float* __restrict__ w_aw, const float* __restrict__ b_aw,
                                                    float* __restrict__ offs, float* __restrict__ araw) {
    int pix = blockIdx.x * 256 + threadIdx.x;
    int nt = blockIdx.y;
    int net = blockIdx.z;
    const float* in = xin + ((size_t)net * NT + nt) * 64 * NPIX + pix;
    if (net == 0) {
        float acc[32];
#pragma unroll
        for (int o = 0; o < 32; o++) acc[o] = b_so[o];
        for (int ci = 0; ci < 64; ci++) {
            float v = in[(size_t)ci * NPIX];
#pragma unroll
            for (int o = 0; o < 32; o++) acc[o] = fmaf(w_so[o * 64 + ci], v, acc[o]);
        }
#pragma unroll
        for (int o = 0; o < 32; o++) offs[((size_t)nt * 32 + o) * NPIX + pix] = acc[o];
    } else {
        float acc[16];
#pragma unroll
        for (int o = 0; o < 16; o++) acc[o] = b_aw[o];
        for (int ci = 0; ci < 64; ci++) {
            float v = in[(size_t)ci * NPIX];
#pragma unroll
            for (int o = 0; o < 16; o++) acc[o] = fmaf(w_aw[o * 64 + ci], v, acc[o]);
        }
#pragma unroll
        for (int o = 0; o < 16; o++) araw[((size_t)nt * 16 + o) * NPIX + pix] = acc[o];
    }
}

// ---- K6: softmax + sample-index precompute ----
__global__ __launch_bounds__(256) void k_softmax_idx(const float* __restrict__ araw,
                                                     const float* __restrict__ offs,
                                                     const float* __restrict__ flow,
                                                     float* __restrict__ attnw, int* __restrict__ sidx) {
    int idx = blockIdx.x * 256 + threadIdx.x;
    if (idx >= 2 * 4 * NPIX) return;
    int pix  = idx % NPIX;
    int head = (idx / NPIX) & 3;
    int n    = idx / (NPIX * 4);
    int x = pix % WSB, y = pix / WSB;
    float a[12];
#pragma unroll
    for (int t = 0; t < 3; t++)
#pragma unroll
        for (int p = 0; p < 4; p++)
            a[t * 4 + p] = araw[(((size_t)(n * 3 + t)) * 16 + head * 4 + p) * NPIX + pix];
    float mx = a[0];
#pragma unroll
    for (int k = 1; k < 12; k++) mx = fmaxf(mx, a[k]);
    float ssum = 0.f;
#pragma unroll
    for (int k = 0; k < 12; k++) { a[k] = expf(a[k] - mx); ssum += a[k]; }
    float inv = 1.0f / ssum;
#pragma unroll
    for (int t = 0; t < 3; t++) {
        int nt = n * 3 + t;
        float fx = flow[((size_t)nt * 2 + 0) * NPIX + pix];
        float fy = flow[((size_t)nt * 2 + 1) * NPIX + pix];
        float locx = fx + (float)x;
        float locy = fy + (float)y;
#pragma unroll
        for (int p = 0; p < 4; p++) {
            int hp = head * 4 + p;
            float gx_ = locx + offs[(((size_t)nt) * 32 + hp * 2 + 0) * NPIX + pix];
            float gy_ = locy + offs[(((size_t)nt) * 32 + hp * 2 + 1) * NPIX + pix];
            float ngx = 2.0f * gx_ / 48.0f - 1.0f;
            float ngy = 2.0f * gy_ / 48.0f - 1.0f;
            float rx = rintf(((ngx + 1.0f) * 0.5f) * 47.0f);
            float ry = rintf(((ngy + 1.0f) * 0.5f) * 47.0f);
            bool valid = (rx >= 0.f) && (rx <= 47.f) && (ry >= 0.f) && (ry <= 47.f);
            int sx = (int)fminf(fmaxf(rx, 0.f), 47.f);
            int sy = (int)fminf(fmaxf(ry, 0.f), 47.f);
            int k = t * 4 + p;
            attnw[(size_t)idx * 12 + k] = valid ? a[k] * inv : 0.f;
            sidx[(size_t)idx * 12 + k]  = sy * WSB + sx;
        }
    }
}

// ---- K6.5 (fallback): transpose ----
__global__ __launch_bounds__(256) void k_transpose(const float* __restrict__ sp,
                                                   u16* __restrict__ spT, int n) {
    __shared__ float tile[64][65];
    int tid = threadIdx.x;
    int pix0 = blockIdx.x * 64;
    int ch0  = blockIdx.y * 64;
    int tl   = blockIdx.z;
    int nt = n * 3 + tl;
    const float* base = sp + ((size_t)nt * 2048 + ch0) * NPIX + pix0;
#pragma unroll
    for (int k = 0; k < 16; k++) {
        int row = k * 4 + (tid >> 6);
        int col = tid & 63;
        tile[row][col] = base[(size_t)row * NPIX + col];
    }
    __syncthreads();
#pragma unroll
    for (int k = 0; k < 2; k++) {
        int task = k * 256 + tid;
        int pl = task >> 3;
        int c0 = (task & 7) * 8;
        u16 pk[8];
#pragma unroll
        for (int j = 0; j < 8; j++) pk[j] = f2bf(tile[c0 + j][pl]);
        *reinterpret_cast<int4*>(spT + ((size_t)tl * NPIX + pix0 + pl) * 2048 + ch0 + c0) =
            *reinterpret_cast<const int4*>(pk);
    }
}

// ---- K7 (fallback): gather -> unpadded NHWC ----
__global__ __launch_bounds__(256) void k_gather2(const u16* __restrict__ spT,
                                                 const float* __restrict__ attnw,
                                                 const int* __restrict__ sidx,
                                                 u16* __restrict__ outimg, int n) {
    __shared__ u16 sArr[2048 + 128];
    int tid = threadIdx.x;
    int pix = blockIdx.x;
    int y = pix / WSB, x = pix % WSB;
    int h = tid >> 6;
    int lane = tid & 63;
    size_t ab = ((size_t)(n * 4 + h) * NPIX + pix) * 12;
    float acc[8] = {};
#pragma unroll
    for (int t = 0; t < 3; t++) {
#pragma unroll
        for (int p = 0; p < 4; p++) {
            int k = t * 4 + p;
            float w = attnw[ab + k];
            int idx = sidx[ab + k];
            bf16x8 v = *reinterpret_cast<const bf16x8*>(
                spT + ((size_t)t * NPIX + idx) * 2048 + h * 512 + lane * 8);
#pragma unroll
            for (int j = 0; j < 8; j++)
                acc[j] = fmaf(w, bf2f((u16)v[j]), acc[j]);
        }
    }
    int c0 = h * 512 + lane * 8;
    int si = c0 + (c0 >> 4);
    u16 pk[8];
#pragma unroll
    for (int j = 0; j < 8; j++) pk[j] = f2bf(acc[j]);
    *reinterpret_cast<int4*>(&sArr[si]) = *reinterpret_cast<const int4*>(pk);
    __syncthreads();
    int opix = tid >> 4;
    int oc0 = (tid & 15) * 8;
    u16 ov[8];
#pragma unroll
    for (int j = 0; j < 8; j++) {
        int oc = oc0 + j;
        int ch = (oc >> 5) * 512 + (oc & 31) * 16 + opix;
        ov[j] = sArr[ch + (ch >> 4)];
    }
    int hq = y * 4 + (opix >> 2);
    int wq = x * 4 + (opix & 3);
    *reinterpret_cast<int4*>(outimg + (((size_t)(n * HH + hq) * WW + wq) << 7) + oc0) =
        *reinterpret_cast<const int4*>(ov);
}

// ---- K7b (big): gather -> PADDED [2][194][194][128] bf16 ----
__global__ __launch_bounds__(256) void k_gather2p(const u16* __restrict__ spT,
                                                  const float* __restrict__ attnw,
                                                  const int* __restrict__ sidx,
                                                  u16* __restrict__ imgP, int n) {
    __shared__ u16 sArr[2048 + 128];
    int tid = threadIdx.x;
    int pix = blockIdx.x;
    int y = pix / WSB, x = pix % WSB;
    int h = tid >> 6;
    int lane = tid & 63;
    size_t ab = ((size_t)(n * 4 + h) * NPIX + pix) * 12;
    float acc[8] = {};
#pragma unroll
    for (int t = 0; t < 3; t++) {
#pragma unroll
        for (int p = 0; p < 4; p++) {
            int k = t * 4 + p;
            float w = attnw[ab + k];
            int idx = sidx[ab + k];
            bf16x8 v = *reinterpret_cast<const bf16x8*>(
                spT + ((size_t)t * NPIX + idx) * 2048 + h * 512 + lane * 8);
#pragma unroll
            for (int j = 0; j < 8; j++)
                acc[j] = fmaf(w, bf2f((u16)v[j]), acc[j]);
        }
    }
    int c0 = h * 512 + lane * 8;
    int si = c0 + (c0 >> 4);
    u16 pk[8];
#pragma unroll
    for (int j = 0; j < 8; j++) pk[j] = f2bf(acc[j]);
    *reinterpret_cast<int4*>(&sArr[si]) = *reinterpret_cast<const int4*>(pk);
    __syncthreads();
    int opix = tid >> 4;
    int oc0 = (tid & 15) * 8;
    u16 ov[8];
#pragma unroll
    for (int j = 0; j < 8; j++) {
        int oc = oc0 + j;
        int ch = (oc >> 5) * 512 + (oc & 31) * 16 + opix;
        ov[j] = sArr[ch + (ch >> 4)];
    }
    int hq = y * 4 + (opix >> 2);
    int wq = x * 4 + (opix & 3);
    *reinterpret_cast<int4*>(imgP + (((size_t)(n * PW + hq + 1) * PW + wq + 1) << 7) + oc0) =
        *reinterpret_cast<const int4*>(ov);
}

// ---- K8 (fallback, R8): fusion via LDS-staged MFMA ----
__global__ __launch_bounds__(256, 3) void k_fusion_mfma(const u16* __restrict__ img,
                                                        const u16* __restrict__ wbf,
                                                        const float* __restrict__ bias,
                                                        const float* __restrict__ anchor,
                                                        float* __restrict__ out) {
    __shared__ __align__(16) u16 lds_in[180 * 128];

    const int tid = threadIdx.x;
    const int px0 = blockIdx.x * 16;
    const int py0 = blockIdx.y * 8;
    const int nb  = blockIdx.z >> 1;
    const int ocq = blockIdx.z & 1;
    const int lane = tid & 63;
    const int w = tid >> 6;
    const int r = lane & 15, g = lane >> 4;

    char* lin_b = reinterpret_cast<char*>(lds_in);

    for (int i = tid; i < 180 * 16; i += 256) {
        int p = i >> 4, c16 = i & 15;
        int hy = p / 18, hx = p % 18;
        int gy = py0 + hy - 1, gx = px0 + hx - 1;
        int4 v = make_int4(0, 0, 0, 0);
        if (gy >= 0 && gy < HH && gx >= 0 && gx < WW)
            v = *reinterpret_cast<const int4*>(img + (((size_t)(nb * HH + gy) * WW + gx) << 7) + (c16 << 3));
        *reinterpret_cast<int4*>(lin_b + p * 256 + (((c16 ^ (p & 7)) << 4))) = v;
    }

    const u16* wb = wbf + (size_t)(ocq * 64 + r) * 32 + g * 8;

    f32x4 acc[2][4] = {};
    bf16x8 b[2][4];
#pragma unroll
    for (int n = 0; n < 4; n++)
        b[0][n] = *reinterpret_cast<const bf16x8*>(wb + (size_t)n * 512);

    __syncthreads();

#pragma unroll
    for (int ph = 0; ph < 36; ph++) {
        const int d = ph >> 2, kc = ph & 3;
        const int dy = d / 3, dx = d % 3;
        if (ph < 35) {
#pragma unroll
            for (int n = 0; n < 4; n++)
                b[(ph + 1) & 1][n] = *reinterpret_cast<const bf16x8*>(
                    wb + (size_t)(ph + 1) * 4096 + (size_t)n * 512);
        }
        const int c16 = kc * 4 + g;
        bf16x8 a[2];
#pragma unroll
        for (int m = 0; m < 2; m++) {
            int hp = (2 * w + m + dy) * 18 + (r + dx);
            a[m] = *reinterpret_cast<const bf16x8*>(lin_b + hp * 256 + (((c16 ^ (hp & 7)) << 4)));
        }
#pragma unroll
        for (int m = 0; m < 2; m++)
#pragma unroll
            for (int n = 0; n < 4; n++)
                acc[m][n] = __builtin_amdgcn_mfma_f32_16x16x32_bf16(a[m], b[ph & 1][n], acc[m][n], 0, 0, 0);
    }

    float bs[4];
#pragma unroll
    for (int n = 0; n < 4; n++) bs[n] = bias[ocq * 64 + n * 16 + r];
#pragma unroll
    for (int m = 0; m < 2; m++) {
        int gy = py0 + 2 * w + m;
#pragma unroll
        for (int n = 0; n < 4; n++) {
            int oc = ocq * 64 + n * 16 + r;
            size_t oa = ((size_t)(nb * CCH + oc)) * (HH * WW) + (size_t)gy * WW + px0 + g * 4;
            f32x4 av = *reinterpret_cast<const f32x4*>(anchor + oa);
            f32x4 res;
#pragma unroll
            for (int q = 0; q < 4; q++) res[q] = acc[m][n][q] + bs[n] + av[q];
            *reinterpret_cast<f32x4*>(out + oa) = res;
        }
    }
}

// ---- K8b (big, R14): LDS-free fusion, padded img, double-buffered A and B ----
// grid (6, 48, 4): z = nb*2 + ocq. Tile 32x4 px x 64 oc. 4 waves: wave w = row w,
// m = x-half (full 128-B-line writes). NO LDS, NO barriers. A-fragments read
// directly from padded img (L1/L2-served); a[2][2] + b[2][4] distance-1
// double-buffers -> each phase's MFMA waits only on the previous phase's loads.
__global__ __launch_bounds__(256, 4) void k_fusion_direct(const u16* __restrict__ imgP,  // [2][194][194][128] bf16
                                                          const u16* __restrict__ wbf,   // bf16 slab layout
                                                          const float* __restrict__ bias,
                                                          const float* __restrict__ anchor,
                                                          float* __restrict__ out) {
    const int tid = threadIdx.x;
    const int px0 = blockIdx.x * 32;
    const int py0 = blockIdx.y * 4;
    const int nb  = blockIdx.z >> 1;
    const int ocq = blockIdx.z & 1;
    const int lane = tid & 63;
    const int w = tid >> 6;
    const int r = lane & 15, g = lane >> 4;

    // A base: gy+1 = py0+w+dy, gx+1 = px0+m*16+r+dx  (padding absorbs the -1)
    const u16* ia = imgP + (((size_t)(nb * PW + py0 + w) * PW + px0 + r) << 7) + g * 8;
    const u16* wb = wbf + (size_t)(ocq * 64 + r) * 32 + g * 8;

    f32x4 acc[2][4] = {};
    bf16x8 b[2][4], a[2][2];
#pragma unroll
    for (int n = 0; n < 4; n++)
        b[0][n] = *reinterpret_cast<const bf16x8*>(wb + (size_t)n * 512);      // ph0: kcd=0
#pragma unroll
    for (int m = 0; m < 2; m++)
        a[0][m] = *reinterpret_cast<const bf16x8*>(ia + ((size_t)(m * 16) << 7)); // ph0: dy=0,dx=0,kc=0

#pragma unroll
    for (int ph = 0; ph < 36; ph++) {
        if (ph < 35) {
            const int ph1 = ph + 1;
            const int d1 = ph1 >> 2, kc1 = ph1 & 3;
            const int dy1 = d1 / 3, dx1 = d1 % 3;
#pragma unroll
            for (int n = 0; n < 4; n++)
                b[ph1 & 1][n] = *reinterpret_cast<const bf16x8*>(
                    wb + (size_t)ph1 * 4096 + (size_t)n * 512);
#pragma unroll
            for (int m = 0; m < 2; m++)
                a[ph1 & 1][m] = *reinterpret_cast<const bf16x8*>(
                    ia + ((size_t)(dy1 * PW + m * 16 + dx1) << 7) + kc1 * 32);
        }
#pragma unroll
        for (int m = 0; m < 2; m++)
#pragma unroll
            for (int n = 0; n < 4; n++)
                acc[m][n] = __builtin_amdgcn_mfma_f32_16x16x32_bf16(a[ph & 1][m], b[ph & 1][n], acc[m][n], 0, 0, 0);
    }

    // epilogue: both x-halves of each 128-B out/anchor line back-to-back (no RMW)
    float bs[4];
#pragma unroll
    for (int n = 0; n < 4; n++) bs[n] = bias[ocq * 64 + n * 16 + r];
    const int gy = py0 + w;
#pragma unroll
    for (int n = 0; n < 4; n++) {
        int oc = ocq * 64 + n * 16 + r;
        size_t rowb = ((size_t)(nb * CCH + oc)) * (HH * WW) + (size_t)gy * WW + px0 + g * 4;
#pragma unroll
        for (int m = 0; m < 2; m++) {
            size_t oa = rowb + m * 16;
            f32x4 av = *reinterpret_cast<const f32x4*>(anchor + oa);
            f32x4 res;
#pragma unroll
            for (int q = 0; q < 4; q++) res[q] = acc[m][n][q] + bs[n] + av[q];
            *reinterpret_cast<f32x4*>(out + oa) = res;
        }
    }
}

extern "C" void kernel_launch(void* const* d_in, const int* in_sizes, int n_in,
                              void* d_out, int out_size, void* d_ws, size_t ws_size,
                              hipStream_t stream) {
    (void)in_sizes; (void)n_in; (void)out_size;
    const float* anchor = (const float*)d_in[1];
    const float* sp     = (const float*)d_in[2];
    const float* flow   = (const float*)d_in[3];
    const float* so_w0 = (const float*)d_in[4];  const float* so_b0 = (const float*)d_in[5];
    const float* so_w1 = (const float*)d_in[6];  const float* so_b1 = (const float*)d_in[7];
    const float* so_w2 = (const float*)d_in[8];  const float* so_b2 = (const float*)d_in[9];
    const float* so_w3 = (const float*)d_in[10]; const float* so_b3 = (const float*)d_in[11];
    const float* aw_w0 = (const float*)d_in[12]; const float* aw_b0 = (const float*)d_in[13];
    const float* aw_w1 = (const float*)d_in[14]; const float* aw_b1 = (const float*)d_in[15];
    const float* aw_w2 = (const float*)d_in[16]; const float* aw_b2 = (const float*)d_in[17];
    const float* aw_w3 = (const float*)d_in[18]; const float* aw_b3 = (const float*)d_in[19];
    const float* fw    = (const float*)d_in[20]; const float* fb    = (const float*)d_in[21];

    float* ws   = (float*)d_ws;
    float* outp = (float*)d_out;
    const bool big = ws_size >= TOTAL2_F32 * 4ull;

    if (big) {
        float* extra = ws + EXTRA2_OFF;
        float* xa    = ws + XA2_OFF;
        float* xb    = ws + XB2_OFF;
        float* offs  = ws + OFFS2_OFF;
        float* araw  = ws + ARAW2_OFF;
        float* wT    = ws + WT2_OFF;
        float* attnw = ws + ATTNW2_OFF;
        int*   sidx  = (int*)(ws + SIDX2_OFF);
        u16*   wbf   = (u16*)(ws + WBF2_OFF);
        u16*   spT2  = (u16*)(ws + SPT2_OFF);
        u16*   imgP  = (u16*)(ws + IMGP_OFF);

        k_wprep<<<dim3(576), 256, 0, stream>>>(fw, wbf);
        k_wprep2<<<dim3(576), 256, 0, stream>>>(so_w1, aw_w1, so_w2, aw_w2, wT);
        k_spprep<<<dim3(36, 32, 6), 256, 0, stream>>>(sp, spT2, extra);
        k_extra_rest<<<dim3((NT * 130 * NPIX + 255) / 256), 256, 0, stream>>>(flow, extra);
        k_conv1x1_l0<<<dim3(9, 6, 8), 256, 0, stream>>>(extra, so_w0, so_b0, aw_w0, aw_b0, xa);
        k_conv3x3<<<dim3(36, 6, 2), 256, 0, stream>>>(xa, wT, so_b1, aw_b1, xb);
        k_conv3x3<<<dim3(36, 6, 2), 256, 0, stream>>>(xb, wT + 73728, so_b2, aw_b2, xa);
        k_conv1x1_l3<<<dim3(9, 6, 2), 256, 0, stream>>>(xa, so_w3, so_b3, aw_w3, aw_b3, offs, araw);
        k_softmax_idx<<<dim3((2 * 4 * NPIX + 255) / 256), 256, 0, stream>>>(araw, offs, flow, attnw, sidx);
        // zero padded img (border must be 0; interior overwritten by gather2p)
        hipMemsetAsync(imgP, 0, (size_t)2 * PW * PW * 128 * sizeof(u16), stream);
        for (int n = 0; n < 2; n++)
            k_gather2p<<<dim3(NPIX), 256, 0, stream>>>(spT2 + (size_t)n * 3 * NPIX * 2048,
                                                       attnw, sidx, imgP, n);
        k_fusion_direct<<<dim3(WW / 32, HH / 4, 4), 256, 0, stream>>>(imgP, wbf, fb, anchor, outp);
    } else {
        float* extra = ws + EXTRA_OFF;
        float* xa    = ws + XA_OFF;
        float* xb    = ws + XB_OFF;
        float* offs  = ws + OFFS_OFF;
        float* araw  = ws + ARAW_OFF;
        float* wT    = ws + WT_OFF;
        float* attnw = ws + ATTNW_OFF;
        int*   sidx  = (int*)(ws + SIDX_OFF);
        u16*   wbf   = (u16*)(ws + WBF_OFF);
        u16*   outimg = (u16*)(ws + OUTIMG_OFF);
        u16*   spT   = (u16*)(ws + SPT_OFF);

        k_wprep<<<dim3(576), 256, 0, stream>>>(fw, wbf);
        k_wprep2<<<dim3(576), 256, 0, stream>>>(so_w1, aw_w1, so_w2, aw_w2, wT);
        k_avgpool<<<dim3((NT * CCH * NPIX + 255) / 256), 256, 0, stream>>>(sp, extra);
        k_extra_rest<<<dim3((NT * 130 * NPIX + 255) / 256), 256, 0, stream>>>(flow, extra);
        k_conv1x1_l0<<<dim3(9, 6, 8), 256, 0, stream>>>(extra, so_w0, so_b0, aw_w0, aw_b0, xa);
        k_conv3x3<<<dim3(36, 6, 2), 256, 0, stream>>>(xa, wT, so_b1, aw_b1, xb);
        k_conv3x3<<<dim3(36, 6, 2), 256, 0, stream>>>(xb, wT + 73728, so_b2, aw_b2, xa);
        k_conv1x1_l3<<<dim3(9, 6, 2), 256, 0, stream>>>(xa, so_w3, so_b3, aw_w3, aw_b3, offs, araw);
        k_softmax_idx<<<dim3((2 * 4 * NPIX + 255) / 256), 256, 0, stream>>>(araw, offs, flow, attnw, sidx);
        for (int n = 0; n < 2; n++) {
            k_transpose<<<dim3(36, 32, 3), 256, 0, stream>>>(sp, spT, n);
            k_gather2<<<dim3(NPIX), 256, 0, stream>>>(spT, attnw, sidx, outimg, n);
        }
        k_fusion_mfma<<<dim3(WW / 16, HH / 8, 4), 256, 0, stream>>>(outimg, wbf, fb, anchor, outp);
    }
}

// Round 15
// 295.236 us; speedup vs baseline: 1.0911x; 1.0911x over previous
//
#include <hip/hip_runtime.h>

typedef unsigned short u16;
typedef unsigned int u32;
typedef __attribute__((ext_vector_type(8))) short bf16x8;
typedef __attribute__((ext_vector_type(4))) float f32x4;

// Problem constants (fixed shapes from setup_inputs)
#define HS   48
#define WSB  48
#define NPIX 2304        // 48*48
#define CCH  128         // c
#define NT   6           // n*t
#define CIN  258         // 2c+2
#define HH   192
#define WW   192

// ---- fallback ws layout (R8/R13, 49.3 MB) ----
#define EXTRA_OFF  0ull
#define OUTIMG_OFF 0ull
#define XA_OFF     4718592ull
#define XB_OFF     6488064ull
#define OFFS_OFF   8257536ull
#define ARAW_OFF   8699904ull
#define WT_OFF     8921088ull
#define SPT_OFF    4718592ull
#define ATTNW_OFF  11796480ull
#define SIDX_OFF   12017664ull
#define WBF_OFF    12238848ull

// ---- big ws layout (fused spprep, 90.4 MB) ----
#define SPT2_OFF    0ull           // bf16 [6nt][2304][2048] = 14,155,776 f32
#define EXTRA2_OFF  14155776ull
#define OUTIMG2_OFF 14155776ull    // overlaps dead extra (+ first part of xa)
#define XA2_OFF     17722368ull
#define XB2_OFF     19491840ull
#define OFFS2_OFF   21261312ull
#define ARAW2_OFF   21703680ull
#define WT2_OFF     21924864ull
#define ATTNW2_OFF  22072320ull
#define SIDX2_OFF   22293504ull
#define WBF2_OFF    22514688ull
#define TOTAL2_F32  22588416ull    // 90,353,664 bytes

static __device__ __forceinline__ float leaky_f(float v) { return v >= 0.f ? v : 0.1f * v; }
static __device__ __forceinline__ u16 f2bf(float f) {
    u32 u = __float_as_uint(f);
    u = (u + 0x7fffu + ((u >> 16) & 1u)) >> 16;
    return (u16)u;
}
static __device__ __forceinline__ float bf2f(u16 v) {
    u32 u = ((u32)v) << 16;
    return __uint_as_float(u);
}

// ---- K0: pack fusion weights to bf16, phase-slab layout ----
// wbf[(d*4+kc)*4096 + oc*32 + g*8 + j]  (u16), ic = kc*32+g*8+j.
__global__ __launch_bounds__(256) void k_wprep(const float* __restrict__ fw, u16* __restrict__ wbf) {
    int i = blockIdx.x * 256 + threadIdx.x;
    int j  = i & 7;
    int g  = (i >> 3) & 3;
    int oc = (i >> 5) & 127;
    int kcd = i >> 12;
    int d = kcd >> 2, kc = kcd & 3;
    int ic = kc * 32 + g * 8 + j;
    wbf[i] = f2bf(fw[((size_t)oc * 128 + ic) * 9 + d]);
}

// ---- K0b: transpose 3x3 net weights to wT[layer][net][ic][tap][oc] (f32) ----
__global__ __launch_bounds__(256) void k_wprep2(const float* __restrict__ so_w1, const float* __restrict__ aw_w1,
                                                const float* __restrict__ so_w2, const float* __restrict__ aw_w2,
                                                float* __restrict__ wT) {
    int i = blockIdx.x * 256 + threadIdx.x;
    int l   = i / 73728;
    int r1  = i % 73728;
    int net = r1 / 36864;
    int r   = r1 % 36864;
    int ic  = r / 576;
    int t2  = r % 576;
    int tap = t2 >> 6, oc = t2 & 63;
    const float* src = l ? (net ? aw_w2 : so_w2) : (net ? aw_w1 : so_w1);
    wT[i] = src[(size_t)oc * 576 + ic * 9 + tap];
}

// ---- K1 (fallback): avgpool ----
__global__ __launch_bounds__(256) void k_avgpool(const float* __restrict__ sp,
                                                 float* __restrict__ extra) {
    int idx = blockIdx.x * 256 + threadIdx.x;
    if (idx >= NT * CCH * NPIX) return;
    int pix = idx % NPIX;
    int cc  = (idx / NPIX) % CCH;
    int nt  = idx / (NPIX * CCH);
    const float* p = sp + ((size_t)nt * 2048 + (size_t)cc * 16) * NPIX + pix;
    float s = 0.f;
#pragma unroll
    for (int k = 0; k < 16; k++) s += p[(size_t)k * NPIX];
    extra[((size_t)nt * CIN + cc) * NPIX + pix] = s * 0.0625f;
}

// ---- K1b (big): fused transpose + avgpool ----
__global__ __launch_bounds__(256) void k_spprep(const float* __restrict__ sp,
                                                u16* __restrict__ spT2,
                                                float* __restrict__ extra) {
    __shared__ float tile[64][65];
    int tid = threadIdx.x;
    int pix0 = blockIdx.x * 64;
    int ch0  = blockIdx.y * 64;
    int nt   = blockIdx.z;
    const float* base = sp + ((size_t)nt * 2048 + ch0) * NPIX + pix0;
#pragma unroll
    for (int k = 0; k < 16; k++) {
        int row = k * 4 + (tid >> 6);
        int col = tid & 63;
        tile[row][col] = base[(size_t)row * NPIX + col];
    }
    __syncthreads();
#pragma unroll
    for (int k = 0; k < 2; k++) {
        int task = k * 256 + tid;
        int pl = task >> 3;
        int c0 = (task & 7) * 8;
        u16 pk[8];
#pragma unroll
        for (int j = 0; j < 8; j++) pk[j] = f2bf(tile[c0 + j][pl]);
        *reinterpret_cast<int4*>(spT2 + ((size_t)nt * NPIX + pix0 + pl) * 2048 + ch0 + c0) =
            *reinterpret_cast<const int4*>(pk);
    }
    {
        int ccl = tid >> 6;
        int col = tid & 63;
        float s = 0.f;
#pragma unroll
        for (int k = 0; k < 16; k++) s += tile[ccl * 16 + k][col];
        int cc = (ch0 >> 4) + ccl;
        extra[((size_t)nt * CIN + cc) * NPIX + pix0 + col] = s * 0.0625f;
    }
}

// ---- K2: extra rest ----
__global__ __launch_bounds__(256) void k_extra_rest(const float* __restrict__ flow,
                                                    float* __restrict__ extra) {
    int idx = blockIdx.x * 256 + threadIdx.x;
    if (idx >= NT * 130 * NPIX) return;
    int pix = idx % NPIX;
    int cc  = (idx / NPIX) % 130;
    int nt  = idx / (NPIX * 130);
    float fx = flow[((size_t)nt * 2 + 0) * NPIX + pix];
    float fy = flow[((size_t)nt * 2 + 1) * NPIX + pix];
    if (cc >= 128) {
        extra[((size_t)nt * CIN + 256 + (cc - 128)) * NPIX + pix] = (cc == 128) ? fx : fy;
        return;
    }
    int x = pix % WSB, y = pix / WSB;
    float locx = fx + (float)x;
    float locy = fy + (float)y;
    float gfx = 2.0f * locx / 47.0f - 1.0f;
    float gfy = 2.0f * locy / 47.0f - 1.0f;
    float rx = rintf(((gfx + 1.0f) * 0.5f) * 47.0f);
    float ry = rintf(((gfy + 1.0f) * 0.5f) * 47.0f);
    bool valid = (rx >= 0.f) && (rx <= 47.f) && (ry >= 0.f) && (ry <= 47.f);
    int sx = (int)fminf(fmaxf(rx, 0.f), 47.f);
    int sy = (int)fminf(fmaxf(ry, 0.f), 47.f);
    float v = valid ? extra[((size_t)nt * CIN + cc) * NPIX + sy * WSB + sx] : 0.f;
    extra[((size_t)nt * CIN + 128 + cc) * NPIX + pix] = v;
}

// ---- K3: 1x1 conv 258->64 + leaky ----
__global__ __launch_bounds__(256) void k_conv1x1_l0(const float* __restrict__ extra,
                                                    const float* __restrict__ w_so, const float* __restrict__ b_so,
                                                    const float* __restrict__ w_aw, const float* __restrict__ b_aw,
                                                    float* __restrict__ xa) {
    __shared__ float ws_[16 * CIN];
    int tile = blockIdx.x;
    int nt   = blockIdx.y;
    int z    = blockIdx.z;
    int net = z >> 2, ocg = z & 3;
    const float* wsel = net ? w_aw : w_so;
    const float* bsel = net ? b_aw : b_so;
    for (int i = threadIdx.x; i < 16 * CIN; i += 256)
        ws_[i] = wsel[(size_t)(ocg * 16) * CIN + i];
    __syncthreads();
    int pix = tile * 256 + threadIdx.x;
    float acc[16];
#pragma unroll
    for (int o = 0; o < 16; o++) acc[o] = bsel[ocg * 16 + o];
    const float* in = extra + (size_t)nt * CIN * NPIX + pix;
    for (int ci = 0; ci < CIN; ci++) {
        float v = in[(size_t)ci * NPIX];
#pragma unroll
        for (int o = 0; o < 16; o++) acc[o] = fmaf(ws_[o * CIN + ci], v, acc[o]);
    }
    float* op = xa + (((size_t)net * NT + nt) * 64 + ocg * 16) * NPIX + pix;
#pragma unroll
    for (int o = 0; o < 16; o++) op[(size_t)o * NPIX] = leaky_f(acc[o]);
}

// ---- K4 (R8): 3x3 conv 64->64 pad1 + leaky, register-tile fp32 ----
__global__ __launch_bounds__(256) void k_conv3x3(const float* __restrict__ xin,
                                                 const float* __restrict__ wT,
                                                 const float* __restrict__ b_so, const float* __restrict__ b_aw,
                                                 float* __restrict__ xout) {
    __shared__ float At[16][6][24];
    __shared__ float Bt[16][9][64];
    int tid = threadIdx.x;
    int txq = tid & 3, tyq = (tid >> 2) & 3, ocg = tid >> 4;
    int st = blockIdx.x;
    int x0 = (st % 3) * 16, y0 = (st / 3) * 4;
    int nt = blockIdx.y, net = blockIdx.z;
    const float* in  = xin + ((size_t)net * NT + nt) * 64 * NPIX;
    const float* wTn = wT + (size_t)net * 36864;
    const float* bsel = net ? b_aw : b_so;

    float acc[4][4];
#pragma unroll
    for (int o = 0; o < 4; o++) {
        float bv = bsel[ocg * 4 + o];
#pragma unroll
        for (int p = 0; p < 4; p++) acc[o][p] = bv;
    }

    for (int c0 = 0; c0 < 64; c0 += 16) {
        __syncthreads();
        for (int i = tid; i < 1728; i += 256) {
            int ic = i / 108, r = i % 108;
            int ry = r / 18, rx = r % 18;
            int gy = y0 + ry - 1, gx = x0 + rx - 1;
            float v = 0.f;
            if (gy >= 0 && gy < HS && gx >= 0 && gx < WSB)
                v = in[(size_t)(c0 + ic) * NPIX + gy * WSB + gx];
            At[ic][ry][rx] = v;
        }
        {
            const float* src = wTn + (size_t)c0 * 576;
            float* dst = &Bt[0][0][0];
            for (int i = tid; i < 9216; i += 256) dst[i] = src[i];
        }
        __syncthreads();
#pragma unroll 2
        for (int ic = 0; ic < 16; ic++) {
#pragma unroll
            for (int dy = 0; dy < 3; dy++) {
                f32x4 a0 = *reinterpret_cast<const f32x4*>(&At[ic][tyq + dy][4 * txq]);
                f32x4 a1 = *reinterpret_cast<const f32x4*>(&At[ic][tyq + dy][4 * txq + 4]);
#pragma unroll
                for (int dx = 0; dx < 3; dx++) {
                    f32x4 bv = *reinterpret_cast<const f32x4*>(&Bt[ic][dy * 3 + dx][4 * ocg]);
#pragma unroll
                    for (int p = 0; p < 4; p++) {
                        float av = (dx + p < 4) ? a0[dx + p] : a1[dx + p - 4];
#pragma unroll
                        for (int o = 0; o < 4; o++)
                            acc[o][p] = fmaf(bv[o], av, acc[o][p]);
                    }
                }
            }
        }
    }

    int py = y0 + tyq, pxb = x0 + 4 * txq;
#pragma unroll
    for (int o = 0; o < 4; o++) {
        f32x4 res;
#pragma unroll
        for (int p = 0; p < 4; p++) res[p] = leaky_f(acc[o][p]);
        float* op = xout + (((size_t)net * NT + nt) * 64 + ocg * 4 + o) * NPIX + py * WSB + pxb;
        *reinterpret_cast<f32x4*>(op) = res;
    }
}

// ---- K5: final 1x1 convs ----
__global__ __launch_bounds__(256) void k_conv1x1_l3(const float* __restrict__ xin,
                                                    const float* __restrict__ w_so, const float* __restrict__ b_so,
                                                    const float* __restrict__ w_aw, const float* __restrict__ b_aw,
                                                    float* __restrict__ offs, float* __restrict__ araw) {
    int pix = blockIdx.x * 256 + threadIdx.x;
    int nt = blockIdx.y;
    int net = blockIdx.z;
    const float* in = xin + ((size_t)net * NT + nt) * 64 * NPIX + pix;
    if (net == 0) {
        float acc[32];
#pragma unroll
        for (int o = 0; o < 32; o++) acc[o] = b_so[o];
        for (int ci = 0; ci < 64; ci++) {
            float v = in[(size_t)ci * NPIX];
#pragma unroll
            for (int o = 0; o < 32; o++) acc[o] = fmaf(w_so[o * 64 + ci], v, acc[o]);
        }
#pragma unroll
        for (int o = 0; o < 32; o++) offs[((size_t)nt * 32 + o) * NPIX + pix] = acc[o];
    } else {
        float acc[16];
#pragma unroll
        for (int o = 0; o < 16; o++) acc[o] = b_aw[o];
        for (int ci = 0; ci < 64; ci++) {
            float v = in[(size_t)ci * NPIX];
#pragma unroll
            for (int o = 0; o < 16; o++) acc[o] = fmaf(w_aw[o * 64 + ci], v, acc[o]);
        }
#pragma unroll
        for (int o = 0; o < 16; o++) araw[((size_t)nt * 16 + o) * NPIX + pix] = acc[o];
    }
}

// ---- K6: softmax + sample-index precompute ----
__global__ __launch_bounds__(256) void k_softmax_idx(const float* __restrict__ araw,
                                                     const float* __restrict__ offs,
                                                     const float* __restrict__ flow,
                                                     float* __restrict__ attnw, int* __restrict__ sidx) {
    int idx = blockIdx.x * 256 + threadIdx.x;
    if (idx >= 2 * 4 * NPIX) return;
    int pix  = idx % NPIX;
    int head = (idx / NPIX) & 3;
    int n    = idx / (NPIX * 4);
    int x = pix % WSB, y = pix / WSB;
    float a[12];
#pragma unroll
    for (int t = 0; t < 3; t++)
#pragma unroll
        for (int p = 0; p < 4; p++)
            a[t * 4 + p] = araw[(((size_t)(n * 3 + t)) * 16 + head * 4 + p) * NPIX + pix];
    float mx = a[0];
#pragma unroll
    for (int k = 1; k < 12; k++) mx = fmaxf(mx, a[k]);
    float ssum = 0.f;
#pragma unroll
    for (int k = 0; k < 12; k++) { a[k] = expf(a[k] - mx); ssum += a[k]; }
    float inv = 1.0f / ssum;
#pragma unroll
    for (int t = 0; t < 3; t++) {
        int nt = n * 3 + t;
        float fx = flow[((size_t)nt * 2 + 0) * NPIX + pix];
        float fy = flow[((size_t)nt * 2 + 1) * NPIX + pix];
        float locx = fx + (float)x;
        float locy = fy + (float)y;
#pragma unroll
        for (int p = 0; p < 4; p++) {
            int hp = head * 4 + p;
            float gx_ = locx + offs[(((size_t)nt) * 32 + hp * 2 + 0) * NPIX + pix];
            float gy_ = locy + offs[(((size_t)nt) * 32 + hp * 2 + 1) * NPIX + pix];
            float ngx = 2.0f * gx_ / 48.0f - 1.0f;
            float ngy = 2.0f * gy_ / 48.0f - 1.0f;
            float rx = rintf(((ngx + 1.0f) * 0.5f) * 47.0f);
            float ry = rintf(((ngy + 1.0f) * 0.5f) * 47.0f);
            bool valid = (rx >= 0.f) && (rx <= 47.f) && (ry >= 0.f) && (ry <= 47.f);
            int sx = (int)fminf(fmaxf(rx, 0.f), 47.f);
            int sy = (int)fminf(fmaxf(ry, 0.f), 47.f);
            int k = t * 4 + p;
            attnw[(size_t)idx * 12 + k] = valid ? a[k] * inv : 0.f;
            sidx[(size_t)idx * 12 + k]  = sy * WSB + sx;
        }
    }
}

// ---- K6.5 (fallback): transpose ----
__global__ __launch_bounds__(256) void k_transpose(const float* __restrict__ sp,
                                                   u16* __restrict__ spT, int n) {
    __shared__ float tile[64][65];
    int tid = threadIdx.x;
    int pix0 = blockIdx.x * 64;
    int ch0  = blockIdx.y * 64;
    int tl   = blockIdx.z;
    int nt = n * 3 + tl;
    const float* base = sp + ((size_t)nt * 2048 + ch0) * NPIX + pix0;
#pragma unroll
    for (int k = 0; k < 16; k++) {
        int row = k * 4 + (tid >> 6);
        int col = tid & 63;
        tile[row][col] = base[(size_t)row * NPIX + col];
    }
    __syncthreads();
#pragma unroll
    for (int k = 0; k < 2; k++) {
        int task = k * 256 + tid;
        int pl = task >> 3;
        int c0 = (task & 7) * 8;
        u16 pk[8];
#pragma unroll
        for (int j = 0; j < 8; j++) pk[j] = f2bf(tile[c0 + j][pl]);
        *reinterpret_cast<int4*>(spT + ((size_t)tl * NPIX + pix0 + pl) * 2048 + ch0 + c0) =
            *reinterpret_cast<const int4*>(pk);
    }
}

// ---- K7: coalesced 12-term gather from spT (per-n base) -> bf16 NHWC outimg ----
__global__ __launch_bounds__(256) void k_gather2(const u16* __restrict__ spT,
                                                 const float* __restrict__ attnw,
                                                 const int* __restrict__ sidx,
                                                 u16* __restrict__ outimg, int n) {
    __shared__ u16 sArr[2048 + 128];
    int tid = threadIdx.x;
    int pix = blockIdx.x;
    int y = pix / WSB, x = pix % WSB;
    int h = tid >> 6;
    int lane = tid & 63;
    size_t ab = ((size_t)(n * 4 + h) * NPIX + pix) * 12;
    float acc[8] = {};
#pragma unroll
    for (int t = 0; t < 3; t++) {
#pragma unroll
        for (int p = 0; p < 4; p++) {
            int k = t * 4 + p;
            float w = attnw[ab + k];
            int idx = sidx[ab + k];
            bf16x8 v = *reinterpret_cast<const bf16x8*>(
                spT + ((size_t)t * NPIX + idx) * 2048 + h * 512 + lane * 8);
#pragma unroll
            for (int j = 0; j < 8; j++)
                acc[j] = fmaf(w, bf2f((u16)v[j]), acc[j]);
        }
    }
    int c0 = h * 512 + lane * 8;
    int si = c0 + (c0 >> 4);
    u16 pk[8];
#pragma unroll
    for (int j = 0; j < 8; j++) pk[j] = f2bf(acc[j]);
    *reinterpret_cast<int4*>(&sArr[si]) = *reinterpret_cast<const int4*>(pk);
    __syncthreads();
    int opix = tid >> 4;
    int oc0 = (tid & 15) * 8;
    u16 ov[8];
#pragma unroll
    for (int j = 0; j < 8; j++) {
        int oc = oc0 + j;
        int ch = (oc >> 5) * 512 + (oc & 31) * 16 + opix;
        ov[j] = sArr[ch + (ch >> 4)];
    }
    int hq = y * 4 + (opix >> 2);
    int wq = x * 4 + (opix & 3);
    *reinterpret_cast<int4*>(outimg + (((size_t)(n * HH + hq) * WW + wq) << 7) + oc0) =
        *reinterpret_cast<const int4*>(ov);
}

// ---- K8 (R15): fusion 3x3 conv, FULL-128-oc MFMA implicit GEMM, zero tail ----
// grid (12, 24, 2): z = nb. 576 blocks = 0.75x co-residency capacity (3/CU via
// 46 KB LDS) -> single scheduling round, halo staged ONCE per tile (was twice
// with the ocq split). Per block: tile 16x8 px x 128 oc; acc[2][8]; weights
// slab-prefetched b[2][8] (each phase's 8 frags come from one 8 KB slab -> L1).
__global__ __launch_bounds__(256, 3) void k_fusion_mfma(const u16* __restrict__ img,   // bf16 NHWC
                                                        const u16* __restrict__ wbf,   // bf16 slab layout
                                                        const float* __restrict__ bias,
                                                        const float* __restrict__ anchor,
                                                        float* __restrict__ out) {
    __shared__ __align__(16) u16 lds_in[180 * 128];   // halo 10x18 x 128ic, swizzled

    const int tid = threadIdx.x;
    const int px0 = blockIdx.x * 16;
    const int py0 = blockIdx.y * 8;
    const int nb  = blockIdx.z;
    const int lane = tid & 63;
    const int w = tid >> 6;
    const int r = lane & 15, g = lane >> 4;

    char* lin_b = reinterpret_cast<char*>(lds_in);

    for (int i = tid; i < 180 * 16; i += 256) {
        int p = i >> 4, c16 = i & 15;
        int hy = p / 18, hx = p % 18;
        int gy = py0 + hy - 1, gx = px0 + hx - 1;
        int4 v = make_int4(0, 0, 0, 0);
        if (gy >= 0 && gy < HH && gx >= 0 && gx < WW)
            v = *reinterpret_cast<const int4*>(img + (((size_t)(nb * HH + gy) * WW + gx) << 7) + (c16 << 3));
        *reinterpret_cast<int4*>(lin_b + p * 256 + (((c16 ^ (p & 7)) << 4))) = v;
    }

    // weight frag base: frag n covers oc = n*16 + r, ic-chunk g of the phase slab
    const u16* wb = wbf + (size_t)r * 32 + g * 8;

    f32x4 acc[2][8] = {};
    bf16x8 b[2][8];
#pragma unroll
    for (int n = 0; n < 8; n++)
        b[0][n] = *reinterpret_cast<const bf16x8*>(wb + (size_t)n * 512);

    __syncthreads();   // the only barrier

#pragma unroll
    for (int ph = 0; ph < 36; ph++) {
        const int d = ph >> 2, kc = ph & 3;
        const int dy = d / 3, dx = d % 3;
        if (ph < 35) {
#pragma unroll
            for (int n = 0; n < 8; n++)
                b[(ph + 1) & 1][n] = *reinterpret_cast<const bf16x8*>(
                    wb + (size_t)(ph + 1) * 4096 + (size_t)n * 512);
        }
        const int c16 = kc * 4 + g;
        bf16x8 a[2];
#pragma unroll
        for (int m = 0; m < 2; m++) {
            int hp = (2 * w + m + dy) * 18 + (r + dx);
            a[m] = *reinterpret_cast<const bf16x8*>(lin_b + hp * 256 + (((c16 ^ (hp & 7)) << 4)));
        }
#pragma unroll
        for (int m = 0; m < 2; m++)
#pragma unroll
            for (int n = 0; n < 8; n++)
                acc[m][n] = __builtin_amdgcn_mfma_f32_16x16x32_bf16(a[m], b[ph & 1][n], acc[m][n], 0, 0, 0);
    }

    float bs[8];
#pragma unroll
    for (int n = 0; n < 8; n++) bs[n] = bias[n * 16 + r];
#pragma unroll
    for (int m = 0; m < 2; m++) {
        int gy = py0 + 2 * w + m;
#pragma unroll
        for (int n = 0; n < 8; n++) {
            int oc = n * 16 + r;
            size_t oa = ((size_t)(nb * CCH + oc)) * (HH * WW) + (size_t)gy * WW + px0 + g * 4;
            f32x4 av = *reinterpret_cast<const f32x4*>(anchor + oa);
            f32x4 res;
#pragma unroll
            for (int q = 0; q < 4; q++) res[q] = acc[m][n][q] + bs[n] + av[q];
            *reinterpret_cast<f32x4*>(out + oa) = res;
        }
    }
}

extern "C" void kernel_launch(void* const* d_in, const int* in_sizes, int n_in,
                              void* d_out, int out_size, void* d_ws, size_t ws_size,
                              hipStream_t stream) {
    (void)in_sizes; (void)n_in; (void)out_size;
    const float* anchor = (const float*)d_in[1];
    const float* sp     = (const float*)d_in[2];
    const float* flow   = (const float*)d_in[3];
    const float* so_w0 = (const float*)d_in[4];  const float* so_b0 = (const float*)d_in[5];
    const float* so_w1 = (const float*)d_in[6];  const float* so_b1 = (const float*)d_in[7];
    const float* so_w2 = (const float*)d_in[8];  const float* so_b2 = (const float*)d_in[9];
    const float* so_w3 = (const float*)d_in[10]; const float* so_b3 = (const float*)d_in[11];
    const float* aw_w0 = (const float*)d_in[12]; const float* aw_b0 = (const float*)d_in[13];
    const float* aw_w1 = (const float*)d_in[14]; const float* aw_b1 = (const float*)d_in[15];
    const float* aw_w2 = (const float*)d_in[16]; const float* aw_b2 = (const float*)d_in[17];
    const float* aw_w3 = (const float*)d_in[18]; const float* aw_b3 = (const float*)d_in[19];
    const float* fw    = (const float*)d_in[20]; const float* fb    = (const float*)d_in[21];

    float* ws   = (float*)d_ws;
    float* outp = (float*)d_out;
    const bool big = ws_size >= TOTAL2_F32 * 4ull;

    float* extra; float* xa; float* xb; float* offs; float* araw; float* wT;
    float* attnw; int* sidx; u16* wbf; u16* outimg;

    if (big) {
        extra = ws + EXTRA2_OFF;  xa = ws + XA2_OFF;    xb = ws + XB2_OFF;
        offs  = ws + OFFS2_OFF;   araw = ws + ARAW2_OFF; wT = ws + WT2_OFF;
        attnw = ws + ATTNW2_OFF;  sidx = (int*)(ws + SIDX2_OFF);
        wbf   = (u16*)(ws + WBF2_OFF);  outimg = (u16*)(ws + OUTIMG2_OFF);
    } else {
        extra = ws + EXTRA_OFF;   xa = ws + XA_OFF;     xb = ws + XB_OFF;
        offs  = ws + OFFS_OFF;    araw = ws + ARAW_OFF;  wT = ws + WT_OFF;
        attnw = ws + ATTNW_OFF;   sidx = (int*)(ws + SIDX_OFF);
        wbf   = (u16*)(ws + WBF_OFF);   outimg = (u16*)(ws + OUTIMG_OFF);
    }

    k_wprep<<<dim3(576), 256, 0, stream>>>(fw, wbf);
    k_wprep2<<<dim3(576), 256, 0, stream>>>(so_w1, aw_w1, so_w2, aw_w2, wT);

    if (big) {
        u16* spT2 = (u16*)(ws + SPT2_OFF);
        k_spprep<<<dim3(36, 32, 6), 256, 0, stream>>>(sp, spT2, extra);
        k_extra_rest<<<dim3((NT * 130 * NPIX + 255) / 256), 256, 0, stream>>>(flow, extra);
        k_conv1x1_l0<<<dim3(9, 6, 8), 256, 0, stream>>>(extra, so_w0, so_b0, aw_w0, aw_b0, xa);
        k_conv3x3<<<dim3(36, 6, 2), 256, 0, stream>>>(xa, wT, so_b1, aw_b1, xb);
        k_conv3x3<<<dim3(36, 6, 2), 256, 0, stream>>>(xb, wT + 73728, so_b2, aw_b2, xa);
        k_conv1x1_l3<<<dim3(9, 6, 2), 256, 0, stream>>>(xa, so_w3, so_b3, aw_w3, aw_b3, offs, araw);
        k_softmax_idx<<<dim3((2 * 4 * NPIX + 255) / 256), 256, 0, stream>>>(araw, offs, flow, attnw, sidx);
        for (int n = 0; n < 2; n++)
            k_gather2<<<dim3(NPIX), 256, 0, stream>>>(spT2 + (size_t)n * 3 * NPIX * 2048,
                                                      attnw, sidx, outimg, n);
    } else {
        u16* spT = (u16*)(ws + SPT_OFF);
        k_avgpool<<<dim3((NT * CCH * NPIX + 255) / 256), 256, 0, stream>>>(sp, extra);
        k_extra_rest<<<dim3((NT * 130 * NPIX + 255) / 256), 256, 0, stream>>>(flow, extra);
        k_conv1x1_l0<<<dim3(9, 6, 8), 256, 0, stream>>>(extra, so_w0, so_b0, aw_w0, aw_b0, xa);
        k_conv3x3<<<dim3(36, 6, 2), 256, 0, stream>>>(xa, wT, so_b1, aw_b1, xb);
        k_conv3x3<<<dim3(36, 6, 2), 256, 0, stream>>>(xb, wT + 73728, so_b2, aw_b2, xa);
        k_conv1x1_l3<<<dim3(9, 6, 2), 256, 0, stream>>>(xa, so_w3, so_b3, aw_w3, aw_b3, offs, araw);
        k_softmax_idx<<<dim3((2 * 4 * NPIX + 255) / 256), 256, 0, stream>>>(araw, offs, flow, attnw, sidx);
        for (int n = 0; n < 2; n++) {
            k_transpose<<<dim3(36, 32, 3), 256, 0, stream>>>(sp, spT, n);
            k_gather2<<<dim3(NPIX), 256, 0, stream>>>(spT, attnw, sidx, outimg, n);
        }
    }
    k_fusion_mfma<<<dim3(WW / 16, HH / 8, 2), 256, 0, stream>>>(outimg, wbf, fb, anchor, outp);
}

// Round 16
// 280.991 us; speedup vs baseline: 1.1464x; 1.0507x over previous
//
#include <hip/hip_runtime.h>

typedef unsigned short u16;
typedef unsigned int u32;
typedef __attribute__((ext_vector_type(8))) short bf16x8;
typedef __attribute__((ext_vector_type(4))) float f32x4;

// Problem constants (fixed shapes from setup_inputs)
#define HS   48
#define WSB  48
#define NPIX 2304        // 48*48
#define CCH  128         // c
#define NT   6           // n*t
#define CIN  258         // 2c+2
#define HH   192
#define WW   192

// ---- fallback ws layout (R8/R13, 49.3 MB) ----
#define EXTRA_OFF  0ull
#define OUTIMG_OFF 0ull
#define XA_OFF     4718592ull
#define XB_OFF     6488064ull
#define OFFS_OFF   8257536ull
#define ARAW_OFF   8699904ull
#define WT_OFF     8921088ull
#define SPT_OFF    4718592ull      // single-n spT, overlaps dead xa/xb/offs/araw/wT
#define ATTNW_OFF  11796480ull
#define SIDX_OFF   12017664ull
#define WBF_OFF    12238848ull

// ---- big ws layout (fused spprep, 90.4 MB) ----
#define SPT2_OFF    0ull           // bf16 [6nt][2304][2048] = 14,155,776 f32
#define EXTRA2_OFF  14155776ull
#define OUTIMG2_OFF 14155776ull    // overlaps dead extra (+ first part of xa)
#define XA2_OFF     17722368ull
#define XB2_OFF     19491840ull
#define OFFS2_OFF   21261312ull
#define ARAW2_OFF   21703680ull
#define WT2_OFF     21924864ull
#define ATTNW2_OFF  22072320ull
#define SIDX2_OFF   22293504ull
#define WBF2_OFF    22514688ull
#define TOTAL2_F32  22588416ull    // 90,353,664 bytes

static __device__ __forceinline__ float leaky_f(float v) { return v >= 0.f ? v : 0.1f * v; }
static __device__ __forceinline__ u16 f2bf(float f) {
    u32 u = __float_as_uint(f);
    u = (u + 0x7fffu + ((u >> 16) & 1u)) >> 16;
    return (u16)u;
}
static __device__ __forceinline__ float bf2f(u16 v) {
    u32 u = ((u32)v) << 16;
    return __uint_as_float(u);
}

// ---- K0: pack fusion weights to bf16, phase-slab layout ----
// wbf[(d*4+kc)*4096 + oc*32 + g*8 + j]  (u16), ic = kc*32+g*8+j.
__global__ __launch_bounds__(256) void k_wprep(const float* __restrict__ fw, u16* __restrict__ wbf) {
    int i = blockIdx.x * 256 + threadIdx.x;
    int j  = i & 7;
    int g  = (i >> 3) & 3;
    int oc = (i >> 5) & 127;
    int kcd = i >> 12;
    int d = kcd >> 2, kc = kcd & 3;
    int ic = kc * 32 + g * 8 + j;
    wbf[i] = f2bf(fw[((size_t)oc * 128 + ic) * 9 + d]);
}

// ---- K0b: transpose 3x3 net weights to wT[layer][net][ic][tap][oc] (f32) ----
__global__ __launch_bounds__(256) void k_wprep2(const float* __restrict__ so_w1, const float* __restrict__ aw_w1,
                                                const float* __restrict__ so_w2, const float* __restrict__ aw_w2,
                                                float* __restrict__ wT) {
    int i = blockIdx.x * 256 + threadIdx.x;
    int l   = i / 73728;
    int r1  = i % 73728;
    int net = r1 / 36864;
    int r   = r1 % 36864;
    int ic  = r / 576;
    int t2  = r % 576;
    int tap = t2 >> 6, oc = t2 & 63;
    const float* src = l ? (net ? aw_w2 : so_w2) : (net ? aw_w1 : so_w1);
    wT[i] = src[(size_t)oc * 576 + ic * 9 + tap];
}

// ---- K1 (fallback): avgpool ----
__global__ __launch_bounds__(256) void k_avgpool(const float* __restrict__ sp,
                                                 float* __restrict__ extra) {
    int idx = blockIdx.x * 256 + threadIdx.x;
    if (idx >= NT * CCH * NPIX) return;
    int pix = idx % NPIX;
    int cc  = (idx / NPIX) % CCH;
    int nt  = idx / (NPIX * CCH);
    const float* p = sp + ((size_t)nt * 2048 + (size_t)cc * 16) * NPIX + pix;
    float s = 0.f;
#pragma unroll
    for (int k = 0; k < 16; k++) s += p[(size_t)k * NPIX];
    extra[((size_t)nt * CIN + cc) * NPIX + pix] = s * 0.0625f;
}

// ---- K1b (big): fused transpose + avgpool: one sp read, both outputs ----
__global__ __launch_bounds__(256) void k_spprep(const float* __restrict__ sp,
                                                u16* __restrict__ spT2,
                                                float* __restrict__ extra) {
    __shared__ float tile[64][65];
    int tid = threadIdx.x;
    int pix0 = blockIdx.x * 64;
    int ch0  = blockIdx.y * 64;
    int nt   = blockIdx.z;
    const float* base = sp + ((size_t)nt * 2048 + ch0) * NPIX + pix0;
#pragma unroll
    for (int k = 0; k < 16; k++) {
        int row = k * 4 + (tid >> 6);
        int col = tid & 63;
        tile[row][col] = base[(size_t)row * NPIX + col];
    }
    __syncthreads();
#pragma unroll
    for (int k = 0; k < 2; k++) {
        int task = k * 256 + tid;
        int pl = task >> 3;
        int c0 = (task & 7) * 8;
        u16 pk[8];
#pragma unroll
        for (int j = 0; j < 8; j++) pk[j] = f2bf(tile[c0 + j][pl]);
        *reinterpret_cast<int4*>(spT2 + ((size_t)nt * NPIX + pix0 + pl) * 2048 + ch0 + c0) =
            *reinterpret_cast<const int4*>(pk);
    }
    {
        int ccl = tid >> 6;
        int col = tid & 63;
        float s = 0.f;
#pragma unroll
        for (int k = 0; k < 16; k++) s += tile[ccl * 16 + k][col];
        int cc = (ch0 >> 4) + ccl;
        extra[((size_t)nt * CIN + cc) * NPIX + pix0 + col] = s * 0.0625f;
    }
}

// ---- K2: extra rest ----
__global__ __launch_bounds__(256) void k_extra_rest(const float* __restrict__ flow,
                                                    float* __restrict__ extra) {
    int idx = blockIdx.x * 256 + threadIdx.x;
    if (idx >= NT * 130 * NPIX) return;
    int pix = idx % NPIX;
    int cc  = (idx / NPIX) % 130;
    int nt  = idx / (NPIX * 130);
    float fx = flow[((size_t)nt * 2 + 0) * NPIX + pix];
    float fy = flow[((size_t)nt * 2 + 1) * NPIX + pix];
    if (cc >= 128) {
        extra[((size_t)nt * CIN + 256 + (cc - 128)) * NPIX + pix] = (cc == 128) ? fx : fy;
        return;
    }
    int x = pix % WSB, y = pix / WSB;
    float locx = fx + (float)x;
    float locy = fy + (float)y;
    float gfx = 2.0f * locx / 47.0f - 1.0f;
    float gfy = 2.0f * locy / 47.0f - 1.0f;
    float rx = rintf(((gfx + 1.0f) * 0.5f) * 47.0f);
    float ry = rintf(((gfy + 1.0f) * 0.5f) * 47.0f);
    bool valid = (rx >= 0.f) && (rx <= 47.f) && (ry >= 0.f) && (ry <= 47.f);
    int sx = (int)fminf(fmaxf(rx, 0.f), 47.f);
    int sy = (int)fminf(fmaxf(ry, 0.f), 47.f);
    float v = valid ? extra[((size_t)nt * CIN + cc) * NPIX + sy * WSB + sx] : 0.f;
    extra[((size_t)nt * CIN + 128 + cc) * NPIX + pix] = v;
}

// ---- K3: 1x1 conv 258->64 + leaky ----
__global__ __launch_bounds__(256) void k_conv1x1_l0(const float* __restrict__ extra,
                                                    const float* __restrict__ w_so, const float* __restrict__ b_so,
                                                    const float* __restrict__ w_aw, const float* __restrict__ b_aw,
                                                    float* __restrict__ xa) {
    __shared__ float ws_[16 * CIN];
    int tile = blockIdx.x;
    int nt   = blockIdx.y;
    int z    = blockIdx.z;
    int net = z >> 2, ocg = z & 3;
    const float* wsel = net ? w_aw : w_so;
    const float* bsel = net ? b_aw : b_so;
    for (int i = threadIdx.x; i < 16 * CIN; i += 256)
        ws_[i] = wsel[(size_t)(ocg * 16) * CIN + i];
    __syncthreads();
    int pix = tile * 256 + threadIdx.x;
    float acc[16];
#pragma unroll
    for (int o = 0; o < 16; o++) acc[o] = bsel[ocg * 16 + o];
    const float* in = extra + (size_t)nt * CIN * NPIX + pix;
    for (int ci = 0; ci < CIN; ci++) {
        float v = in[(size_t)ci * NPIX];
#pragma unroll
        for (int o = 0; o < 16; o++) acc[o] = fmaf(ws_[o * CIN + ci], v, acc[o]);
    }
    float* op = xa + (((size_t)net * NT + nt) * 64 + ocg * 16) * NPIX + pix;
#pragma unroll
    for (int o = 0; o < 16; o++) op[(size_t)o * NPIX] = leaky_f(acc[o]);
}

// ---- K4 (R8): 3x3 conv 64->64 pad1 + leaky, register-tile fp32 ----
__global__ __launch_bounds__(256) void k_conv3x3(const float* __restrict__ xin,
                                                 const float* __restrict__ wT,    // [net][64ic][9][64oc]
                                                 const float* __restrict__ b_so, const float* __restrict__ b_aw,
                                                 float* __restrict__ xout) {
    __shared__ float At[16][6][24];
    __shared__ float Bt[16][9][64];
    int tid = threadIdx.x;
    int txq = tid & 3, tyq = (tid >> 2) & 3, ocg = tid >> 4;
    int st = blockIdx.x;
    int x0 = (st % 3) * 16, y0 = (st / 3) * 4;
    int nt = blockIdx.y, net = blockIdx.z;
    const float* in  = xin + ((size_t)net * NT + nt) * 64 * NPIX;
    const float* wTn = wT + (size_t)net * 36864;
    const float* bsel = net ? b_aw : b_so;

    float acc[4][4];   // [oc][px]
#pragma unroll
    for (int o = 0; o < 4; o++) {
        float bv = bsel[ocg * 4 + o];
#pragma unroll
        for (int p = 0; p < 4; p++) acc[o][p] = bv;
    }

    for (int c0 = 0; c0 < 64; c0 += 16) {
        __syncthreads();
        for (int i = tid; i < 1728; i += 256) {
            int ic = i / 108, r = i % 108;
            int ry = r / 18, rx = r % 18;
            int gy = y0 + ry - 1, gx = x0 + rx - 1;
            float v = 0.f;
            if (gy >= 0 && gy < HS && gx >= 0 && gx < WSB)
                v = in[(size_t)(c0 + ic) * NPIX + gy * WSB + gx];
            At[ic][ry][rx] = v;
        }
        {
            const float* src = wTn + (size_t)c0 * 576;
            float* dst = &Bt[0][0][0];
            for (int i = tid; i < 9216; i += 256) dst[i] = src[i];
        }
        __syncthreads();
#pragma unroll 2
        for (int ic = 0; ic < 16; ic++) {
#pragma unroll
            for (int dy = 0; dy < 3; dy++) {
                f32x4 a0 = *reinterpret_cast<const f32x4*>(&At[ic][tyq + dy][4 * txq]);
                f32x4 a1 = *reinterpret_cast<const f32x4*>(&At[ic][tyq + dy][4 * txq + 4]);
#pragma unroll
                for (int dx = 0; dx < 3; dx++) {
                    f32x4 bv = *reinterpret_cast<const f32x4*>(&Bt[ic][dy * 3 + dx][4 * ocg]);
#pragma unroll
                    for (int p = 0; p < 4; p++) {
                        float av = (dx + p < 4) ? a0[dx + p] : a1[dx + p - 4];
#pragma unroll
                        for (int o = 0; o < 4; o++)
                            acc[o][p] = fmaf(bv[o], av, acc[o][p]);
                    }
                }
            }
        }
    }

    int py = y0 + tyq, pxb = x0 + 4 * txq;
#pragma unroll
    for (int o = 0; o < 4; o++) {
        f32x4 res;
#pragma unroll
        for (int p = 0; p < 4; p++) res[p] = leaky_f(acc[o][p]);
        float* op = xout + (((size_t)net * NT + nt) * 64 + ocg * 4 + o) * NPIX + py * WSB + pxb;
        *reinterpret_cast<f32x4*>(op) = res;
    }
}

// ---- K5: final 1x1 convs ----
__global__ __launch_bounds__(256) void k_conv1x1_l3(const float* __restrict__ xin,
                                                    const float* __restrict__ w_so, const float* __restrict__ b_so,
                                                    const float* __restrict__ w_aw, const float* __restrict__ b_aw,
                                                    float* __restrict__ offs, float* __restrict__ araw) {
    int pix = blockIdx.x * 256 + threadIdx.x;
    int nt = blockIdx.y;
    int net = blockIdx.z;
    const float* in = xin + ((size_t)net * NT + nt) * 64 * NPIX + pix;
    if (net == 0) {
        float acc[32];
#pragma unroll
        for (int o = 0; o < 32; o++) acc[o] = b_so[o];
        for (int ci = 0; ci < 64; ci++) {
            float v = in[(size_t)ci * NPIX];
#pragma unroll
            for (int o = 0; o < 32; o++) acc[o] = fmaf(w_so[o * 64 + ci], v, acc[o]);
        }
#pragma unroll
        for (int o = 0; o < 32; o++) offs[((size_t)nt * 32 + o) * NPIX + pix] = acc[o];
    } else {
        float acc[16];
#pragma unroll
        for (int o = 0; o < 16; o++) acc[o] = b_aw[o];
        for (int ci = 0; ci < 64; ci++) {
            float v = in[(size_t)ci * NPIX];
#pragma unroll
            for (int o = 0; o < 16; o++) acc[o] = fmaf(w_aw[o * 64 + ci], v, acc[o]);
        }
#pragma unroll
        for (int o = 0; o < 16; o++) araw[((size_t)nt * 16 + o) * NPIX + pix] = acc[o];
    }
}

// ---- K6: softmax over 12 (t,p) + sample-index precompute ----
__global__ __launch_bounds__(256) void k_softmax_idx(const float* __restrict__ araw,
                                                     const float* __restrict__ offs,
                                                     const float* __restrict__ flow,
                                                     float* __restrict__ attnw, int* __restrict__ sidx) {
    int idx = blockIdx.x * 256 + threadIdx.x;
    if (idx >= 2 * 4 * NPIX) return;
    int pix  = idx % NPIX;
    int head = (idx / NPIX) & 3;
    int n    = idx / (NPIX * 4);
    int x = pix % WSB, y = pix / WSB;
    float a[12];
#pragma unroll
    for (int t = 0; t < 3; t++)
#pragma unroll
        for (int p = 0; p < 4; p++)
            a[t * 4 + p] = araw[(((size_t)(n * 3 + t)) * 16 + head * 4 + p) * NPIX + pix];
    float mx = a[0];
#pragma unroll
    for (int k = 1; k < 12; k++) mx = fmaxf(mx, a[k]);
    float ssum = 0.f;
#pragma unroll
    for (int k = 0; k < 12; k++) { a[k] = expf(a[k] - mx); ssum += a[k]; }
    float inv = 1.0f / ssum;
#pragma unroll
    for (int t = 0; t < 3; t++) {
        int nt = n * 3 + t;
        float fx = flow[((size_t)nt * 2 + 0) * NPIX + pix];
        float fy = flow[((size_t)nt * 2 + 1) * NPIX + pix];
        float locx = fx + (float)x;
        float locy = fy + (float)y;
#pragma unroll
        for (int p = 0; p < 4; p++) {
            int hp = head * 4 + p;
            float gx_ = locx + offs[(((size_t)nt) * 32 + hp * 2 + 0) * NPIX + pix];
            float gy_ = locy + offs[(((size_t)nt) * 32 + hp * 2 + 1) * NPIX + pix];
            float ngx = 2.0f * gx_ / 48.0f - 1.0f;
            float ngy = 2.0f * gy_ / 48.0f - 1.0f;
            float rx = rintf(((ngx + 1.0f) * 0.5f) * 47.0f);
            float ry = rintf(((ngy + 1.0f) * 0.5f) * 47.0f);
            bool valid = (rx >= 0.f) && (rx <= 47.f) && (ry >= 0.f) && (ry <= 47.f);
            int sx = (int)fminf(fmaxf(rx, 0.f), 47.f);
            int sy = (int)fminf(fmaxf(ry, 0.f), 47.f);
            int k = t * 4 + p;
            attnw[(size_t)idx * 12 + k] = valid ? a[k] * inv : 0.f;
            sidx[(size_t)idx * 12 + k]  = sy * WSB + sx;
        }
    }
}

// ---- K6.5 (fallback): per-n transpose sp -> spT[t][pix][2048] bf16 ----
__global__ __launch_bounds__(256) void k_transpose(const float* __restrict__ sp,
                                                   u16* __restrict__ spT, int n) {
    __shared__ float tile[64][65];
    int tid = threadIdx.x;
    int pix0 = blockIdx.x * 64;
    int ch0  = blockIdx.y * 64;
    int tl   = blockIdx.z;
    int nt = n * 3 + tl;
    const float* base = sp + ((size_t)nt * 2048 + ch0) * NPIX + pix0;
#pragma unroll
    for (int k = 0; k < 16; k++) {
        int row = k * 4 + (tid >> 6);
        int col = tid & 63;
        tile[row][col] = base[(size_t)row * NPIX + col];
    }
    __syncthreads();
#pragma unroll
    for (int k = 0; k < 2; k++) {
        int task = k * 256 + tid;
        int pl = task >> 3;
        int c0 = (task & 7) * 8;
        u16 pk[8];
#pragma unroll
        for (int j = 0; j < 8; j++) pk[j] = f2bf(tile[c0 + j][pl]);
        *reinterpret_cast<int4*>(spT + ((size_t)tl * NPIX + pix0 + pl) * 2048 + ch0 + c0) =
            *reinterpret_cast<const int4*>(pk);
    }
}

// ---- K7: coalesced 12-term gather from spT (per-n base) -> bf16 NHWC outimg ----
__global__ __launch_bounds__(256) void k_gather2(const u16* __restrict__ spT,
                                                 const float* __restrict__ attnw,
                                                 const int* __restrict__ sidx,
                                                 u16* __restrict__ outimg, int n) {
    __shared__ u16 sArr[2048 + 128];
    int tid = threadIdx.x;
    int pix = blockIdx.x;
    int y = pix / WSB, x = pix % WSB;
    int h = tid >> 6;
    int lane = tid & 63;
    size_t ab = ((size_t)(n * 4 + h) * NPIX + pix) * 12;
    float acc[8] = {};
#pragma unroll
    for (int t = 0; t < 3; t++) {
#pragma unroll
        for (int p = 0; p < 4; p++) {
            int k = t * 4 + p;
            float w = attnw[ab + k];
            int idx = sidx[ab + k];
            bf16x8 v = *reinterpret_cast<const bf16x8*>(
                spT + ((size_t)t * NPIX + idx) * 2048 + h * 512 + lane * 8);
#pragma unroll
            for (int j = 0; j < 8; j++)
                acc[j] = fmaf(w, bf2f((u16)v[j]), acc[j]);
        }
    }
    int c0 = h * 512 + lane * 8;
    int si = c0 + (c0 >> 4);
    u16 pk[8];
#pragma unroll
    for (int j = 0; j < 8; j++) pk[j] = f2bf(acc[j]);
    *reinterpret_cast<int4*>(&sArr[si]) = *reinterpret_cast<const int4*>(pk);
    __syncthreads();
    int opix = tid >> 4;
    int oc0 = (tid & 15) * 8;
    u16 ov[8];
#pragma unroll
    for (int j = 0; j < 8; j++) {
        int oc = oc0 + j;
        int ch = (oc >> 5) * 512 + (oc & 31) * 16 + opix;
        ov[j] = sArr[ch + (ch >> 4)];
    }
    int hq = y * 4 + (opix >> 2);
    int wq = x * 4 + (opix & 3);
    *reinterpret_cast<int4*>(outimg + (((size_t)(n * HH + hq) * WW + wq) << 7) + oc0) =
        *reinterpret_cast<const int4*>(ov);
}

// ---- K8 (R8): fusion 3x3 conv, oc-split MFMA implicit GEMM ----
__global__ __launch_bounds__(256, 3) void k_fusion_mfma(const u16* __restrict__ img,   // bf16 NHWC
                                                        const u16* __restrict__ wbf,   // bf16 slab layout
                                                        const float* __restrict__ bias,
                                                        const float* __restrict__ anchor,
                                                        float* __restrict__ out) {
    __shared__ __align__(16) u16 lds_in[180 * 128];   // halo 10x18 x 128ic, swizzled

    const int tid = threadIdx.x;
    const int px0 = blockIdx.x * 16;
    const int py0 = blockIdx.y * 8;
    const int nb  = blockIdx.z >> 1;
    const int ocq = blockIdx.z & 1;
    const int lane = tid & 63;
    const int w = tid >> 6;
    const int r = lane & 15, g = lane >> 4;

    char* lin_b = reinterpret_cast<char*>(lds_in);

    for (int i = tid; i < 180 * 16; i += 256) {
        int p = i >> 4, c16 = i & 15;
        int hy = p / 18, hx = p % 18;
        int gy = py0 + hy - 1, gx = px0 + hx - 1;
        int4 v = make_int4(0, 0, 0, 0);
        if (gy >= 0 && gy < HH && gx >= 0 && gx < WW)
            v = *reinterpret_cast<const int4*>(img + (((size_t)(nb * HH + gy) * WW + gx) << 7) + (c16 << 3));
        *reinterpret_cast<int4*>(lin_b + p * 256 + (((c16 ^ (p & 7)) << 4))) = v;
    }

    const u16* wb = wbf + (size_t)(ocq * 64 + r) * 32 + g * 8;

    f32x4 acc[2][4] = {};
    bf16x8 b[2][4];
#pragma unroll
    for (int n = 0; n < 4; n++)
        b[0][n] = *reinterpret_cast<const bf16x8*>(wb + (size_t)n * 512);

    __syncthreads();

#pragma unroll
    for (int ph = 0; ph < 36; ph++) {
        const int d = ph >> 2, kc = ph & 3;
        const int dy = d / 3, dx = d % 3;
        if (ph < 35) {
#pragma unroll
            for (int n = 0; n < 4; n++)
                b[(ph + 1) & 1][n] = *reinterpret_cast<const bf16x8*>(
                    wb + (size_t)(ph + 1) * 4096 + (size_t)n * 512);
        }
        const int c16 = kc * 4 + g;
        bf16x8 a[2];
#pragma unroll
        for (int m = 0; m < 2; m++) {
            int hp = (2 * w + m + dy) * 18 + (r + dx);
            a[m] = *reinterpret_cast<const bf16x8*>(lin_b + hp * 256 + (((c16 ^ (hp & 7)) << 4)));
        }
#pragma unroll
        for (int m = 0; m < 2; m++)
#pragma unroll
            for (int n = 0; n < 4; n++)
                acc[m][n] = __builtin_amdgcn_mfma_f32_16x16x32_bf16(a[m], b[ph & 1][n], acc[m][n], 0, 0, 0);
    }

    float bs[4];
#pragma unroll
    for (int n = 0; n < 4; n++) bs[n] = bias[ocq * 64 + n * 16 + r];
#pragma unroll
    for (int m = 0; m < 2; m++) {
        int gy = py0 + 2 * w + m;
#pragma unroll
        for (int n = 0; n < 4; n++) {
            int oc = ocq * 64 + n * 16 + r;
            size_t oa = ((size_t)(nb * CCH + oc)) * (HH * WW) + (size_t)gy * WW + px0 + g * 4;
            f32x4 av = *reinterpret_cast<const f32x4*>(anchor + oa);
            f32x4 res;
#pragma unroll
            for (int q = 0; q < 4; q++) res[q] = acc[m][n][q] + bs[n] + av[q];
            *reinterpret_cast<f32x4*>(out + oa) = res;
        }
    }
}

extern "C" void kernel_launch(void* const* d_in, const int* in_sizes, int n_in,
                              void* d_out, int out_size, void* d_ws, size_t ws_size,
                              hipStream_t stream) {
    (void)in_sizes; (void)n_in; (void)out_size;
    const float* anchor = (const float*)d_in[1];
    const float* sp     = (const float*)d_in[2];
    const float* flow   = (const float*)d_in[3];
    const float* so_w0 = (const float*)d_in[4];  const float* so_b0 = (const float*)d_in[5];
    const float* so_w1 = (const float*)d_in[6];  const float* so_b1 = (const float*)d_in[7];
    const float* so_w2 = (const float*)d_in[8];  const float* so_b2 = (const float*)d_in[9];
    const float* so_w3 = (const float*)d_in[10]; const float* so_b3 = (const float*)d_in[11];
    const float* aw_w0 = (const float*)d_in[12]; const float* aw_b0 = (const float*)d_in[13];
    const float* aw_w1 = (const float*)d_in[14]; const float* aw_b1 = (const float*)d_in[15];
    const float* aw_w2 = (const float*)d_in[16]; const float* aw_b2 = (const float*)d_in[17];
    const float* aw_w3 = (const float*)d_in[18]; const float* aw_b3 = (const float*)d_in[19];
    const float* fw    = (const float*)d_in[20]; const float* fb    = (const float*)d_in[21];

    float* ws   = (float*)d_ws;
    float* outp = (float*)d_out;
    const bool big = ws_size >= TOTAL2_F32 * 4ull;

    float* extra; float* xa; float* xb; float* offs; float* araw; float* wT;
    float* attnw; int* sidx; u16* wbf; u16* outimg;

    if (big) {
        extra = ws + EXTRA2_OFF;  xa = ws + XA2_OFF;    xb = ws + XB2_OFF;
        offs  = ws + OFFS2_OFF;   araw = ws + ARAW2_OFF; wT = ws + WT2_OFF;
        attnw = ws + ATTNW2_OFF;  sidx = (int*)(ws + SIDX2_OFF);
        wbf   = (u16*)(ws + WBF2_OFF);  outimg = (u16*)(ws + OUTIMG2_OFF);
    } else {
        extra = ws + EXTRA_OFF;   xa = ws + XA_OFF;     xb = ws + XB_OFF;
        offs  = ws + OFFS_OFF;    araw = ws + ARAW_OFF;  wT = ws + WT_OFF;
        attnw = ws + ATTNW_OFF;   sidx = (int*)(ws + SIDX_OFF);
        wbf   = (u16*)(ws + WBF_OFF);   outimg = (u16*)(ws + OUTIMG_OFF);
    }

    k_wprep<<<dim3(576), 256, 0, stream>>>(fw, wbf);
    k_wprep2<<<dim3(576), 256, 0, stream>>>(so_w1, aw_w1, so_w2, aw_w2, wT);

    if (big) {
        u16* spT2 = (u16*)(ws + SPT2_OFF);
        k_spprep<<<dim3(36, 32, 6), 256, 0, stream>>>(sp, spT2, extra);
        k_extra_rest<<<dim3((NT * 130 * NPIX + 255) / 256), 256, 0, stream>>>(flow, extra);
        k_conv1x1_l0<<<dim3(9, 6, 8), 256, 0, stream>>>(extra, so_w0, so_b0, aw_w0, aw_b0, xa);
        k_conv3x3<<<dim3(36, 6, 2), 256, 0, stream>>>(xa, wT, so_b1, aw_b1, xb);
        k_conv3x3<<<dim3(36, 6, 2), 256, 0, stream>>>(xb, wT + 73728, so_b2, aw_b2, xa);
        k_conv1x1_l3<<<dim3(9, 6, 2), 256, 0, stream>>>(xa, so_w3, so_b3, aw_w3, aw_b3, offs, araw);
        k_softmax_idx<<<dim3((2 * 4 * NPIX + 255) / 256), 256, 0, stream>>>(araw, offs, flow, attnw, sidx);
        for (int n = 0; n < 2; n++)
            k_gather2<<<dim3(NPIX), 256, 0, stream>>>(spT2 + (size_t)n * 3 * NPIX * 2048,
                                                      attnw, sidx, outimg, n);
    } else {
        u16* spT = (u16*)(ws + SPT_OFF);
        k_avgpool<<<dim3((NT * CCH * NPIX + 255) / 256), 256, 0, stream>>>(sp, extra);
        k_extra_rest<<<dim3((NT * 130 * NPIX + 255) / 256), 256, 0, stream>>>(flow, extra);
        k_conv1x1_l0<<<dim3(9, 6, 8), 256, 0, stream>>>(extra, so_w0, so_b0, aw_w0, aw_b0, xa);
        k_conv3x3<<<dim3(36, 6, 2), 256, 0, stream>>>(xa, wT, so_b1, aw_b1, xb);
        k_conv3x3<<<dim3(36, 6, 2), 256, 0, stream>>>(xb, wT + 73728, so_b2, aw_b2, xa);
        k_conv1x1_l3<<<dim3(9, 6, 2), 256, 0, stream>>>(xa, so_w3, so_b3, aw_w3, aw_b3, offs, araw);
        k_softmax_idx<<<dim3((2 * 4 * NPIX + 255) / 256), 256, 0, stream>>>(araw, offs, flow, attnw, sidx);
        for (int n = 0; n < 2; n++) {
            k_transpose<<<dim3(36, 32, 3), 256, 0, stream>>>(sp, spT, n);
            k_gather2<<<dim3(NPIX), 256, 0, stream>>>(spT, attnw, sidx, outimg, n);
        }
    }
    k_fusion_mfma<<<dim3(WW / 16, HH / 8, 4), 256, 0, stream>>>(outimg, wbf, fb, anchor, outp);
}

// Round 17
// 279.186 us; speedup vs baseline: 1.1539x; 1.0065x over previous
//
#include <hip/hip_runtime.h>

typedef unsigned short u16;
typedef unsigned int u32;
typedef __attribute__((ext_vector_type(8))) short bf16x8;
typedef __attribute__((ext_vector_type(4))) float f32x4;

// Problem constants (fixed shapes from setup_inputs)
#define HS   48
#define WSB  48
#define NPIX 2304        // 48*48
#define CCH  128         // c
#define NT   6           // n*t
#define CIN  258         // 2c+2
#define HH   192
#define WW   192

// ---- fallback ws layout (R8/R13, 49.3 MB) ----
#define EXTRA_OFF  0ull
#define OUTIMG_OFF 0ull
#define XA_OFF     4718592ull
#define XB_OFF     6488064ull
#define OFFS_OFF   8257536ull
#define ARAW_OFF   8699904ull
#define WT_OFF     8921088ull
#define SPT_OFF    4718592ull      // single-n spT, overlaps dead xa/xb/offs/araw/wT
#define ATTNW_OFF  11796480ull
#define SIDX_OFF   12017664ull
#define WBF_OFF    12238848ull

// ---- big ws layout (fused spprep, 90.4 MB) ----
#define SPT2_OFF    0ull           // bf16 [6nt][2304][2048] = 14,155,776 f32
#define EXTRA2_OFF  14155776ull
#define OUTIMG2_OFF 14155776ull    // overlaps dead extra (+ first part of xa)
#define XA2_OFF     17722368ull
#define XB2_OFF     19491840ull
#define OFFS2_OFF   21261312ull
#define ARAW2_OFF   21703680ull
#define WT2_OFF     21924864ull
#define ATTNW2_OFF  22072320ull
#define SIDX2_OFF   22293504ull
#define WBF2_OFF    22514688ull
#define TOTAL2_F32  22588416ull    // 90,353,664 bytes

static __device__ __forceinline__ float leaky_f(float v) { return v >= 0.f ? v : 0.1f * v; }
static __device__ __forceinline__ u16 f2bf(float f) {
    u32 u = __float_as_uint(f);
    u = (u + 0x7fffu + ((u >> 16) & 1u)) >> 16;
    return (u16)u;
}
static __device__ __forceinline__ float bf2f(u16 v) {
    u32 u = ((u32)v) << 16;
    return __uint_as_float(u);
}

// ---- K0: pack fusion weights to bf16, phase-slab layout ----
// wbf[(d*4+kc)*4096 + oc*32 + g*8 + j]  (u16), ic = kc*32+g*8+j.
__global__ __launch_bounds__(256) void k_wprep(const float* __restrict__ fw, u16* __restrict__ wbf) {
    int i = blockIdx.x * 256 + threadIdx.x;
    int j  = i & 7;
    int g  = (i >> 3) & 3;
    int oc = (i >> 5) & 127;
    int kcd = i >> 12;
    int d = kcd >> 2, kc = kcd & 3;
    int ic = kc * 32 + g * 8 + j;
    wbf[i] = f2bf(fw[((size_t)oc * 128 + ic) * 9 + d]);
}

// ---- K0b: transpose 3x3 net weights to wT[layer][net][ic][tap][oc] (f32) ----
__global__ __launch_bounds__(256) void k_wprep2(const float* __restrict__ so_w1, const float* __restrict__ aw_w1,
                                                const float* __restrict__ so_w2, const float* __restrict__ aw_w2,
                                                float* __restrict__ wT) {
    int i = blockIdx.x * 256 + threadIdx.x;
    int l   = i / 73728;
    int r1  = i % 73728;
    int net = r1 / 36864;
    int r   = r1 % 36864;
    int ic  = r / 576;
    int t2  = r % 576;
    int tap = t2 >> 6, oc = t2 & 63;
    const float* src = l ? (net ? aw_w2 : so_w2) : (net ? aw_w1 : so_w1);
    wT[i] = src[(size_t)oc * 576 + ic * 9 + tap];
}

// ---- K1 (fallback): avgpool ----
__global__ __launch_bounds__(256) void k_avgpool(const float* __restrict__ sp,
                                                 float* __restrict__ extra) {
    int idx = blockIdx.x * 256 + threadIdx.x;
    if (idx >= NT * CCH * NPIX) return;
    int pix = idx % NPIX;
    int cc  = (idx / NPIX) % CCH;
    int nt  = idx / (NPIX * CCH);
    const float* p = sp + ((size_t)nt * 2048 + (size_t)cc * 16) * NPIX + pix;
    float s = 0.f;
#pragma unroll
    for (int k = 0; k < 16; k++) s += p[(size_t)k * NPIX];
    extra[((size_t)nt * CIN + cc) * NPIX + pix] = s * 0.0625f;
}

// ---- K1b (big): fused transpose + avgpool: one sp read, both outputs ----
__global__ __launch_bounds__(256) void k_spprep(const float* __restrict__ sp,
                                                u16* __restrict__ spT2,
                                                float* __restrict__ extra) {
    __shared__ float tile[64][65];
    int tid = threadIdx.x;
    int pix0 = blockIdx.x * 64;
    int ch0  = blockIdx.y * 64;
    int nt   = blockIdx.z;
    const float* base = sp + ((size_t)nt * 2048 + ch0) * NPIX + pix0;
#pragma unroll
    for (int k = 0; k < 16; k++) {
        int row = k * 4 + (tid >> 6);
        int col = tid & 63;
        tile[row][col] = base[(size_t)row * NPIX + col];
    }
    __syncthreads();
#pragma unroll
    for (int k = 0; k < 2; k++) {
        int task = k * 256 + tid;
        int pl = task >> 3;
        int c0 = (task & 7) * 8;
        u16 pk[8];
#pragma unroll
        for (int j = 0; j < 8; j++) pk[j] = f2bf(tile[c0 + j][pl]);
        *reinterpret_cast<int4*>(spT2 + ((size_t)nt * NPIX + pix0 + pl) * 2048 + ch0 + c0) =
            *reinterpret_cast<const int4*>(pk);
    }
    {
        int ccl = tid >> 6;
        int col = tid & 63;
        float s = 0.f;
#pragma unroll
        for (int k = 0; k < 16; k++) s += tile[ccl * 16 + k][col];
        int cc = (ch0 >> 4) + ccl;
        extra[((size_t)nt * CIN + cc) * NPIX + pix0 + col] = s * 0.0625f;
    }
}

// ---- K2: extra rest ----
__global__ __launch_bounds__(256) void k_extra_rest(const float* __restrict__ flow,
                                                    float* __restrict__ extra) {
    int idx = blockIdx.x * 256 + threadIdx.x;
    if (idx >= NT * 130 * NPIX) return;
    int pix = idx % NPIX;
    int cc  = (idx / NPIX) % 130;
    int nt  = idx / (NPIX * 130);
    float fx = flow[((size_t)nt * 2 + 0) * NPIX + pix];
    float fy = flow[((size_t)nt * 2 + 1) * NPIX + pix];
    if (cc >= 128) {
        extra[((size_t)nt * CIN + 256 + (cc - 128)) * NPIX + pix] = (cc == 128) ? fx : fy;
        return;
    }
    int x = pix % WSB, y = pix / WSB;
    float locx = fx + (float)x;
    float locy = fy + (float)y;
    float gfx = 2.0f * locx / 47.0f - 1.0f;
    float gfy = 2.0f * locy / 47.0f - 1.0f;
    float rx = rintf(((gfx + 1.0f) * 0.5f) * 47.0f);
    float ry = rintf(((gfy + 1.0f) * 0.5f) * 47.0f);
    bool valid = (rx >= 0.f) && (rx <= 47.f) && (ry >= 0.f) && (ry <= 47.f);
    int sx = (int)fminf(fmaxf(rx, 0.f), 47.f);
    int sy = (int)fminf(fmaxf(ry, 0.f), 47.f);
    float v = valid ? extra[((size_t)nt * CIN + cc) * NPIX + sy * WSB + sx] : 0.f;
    extra[((size_t)nt * CIN + 128 + cc) * NPIX + pix] = v;
}

// ---- K3: 1x1 conv 258->64 + leaky ----
__global__ __launch_bounds__(256) void k_conv1x1_l0(const float* __restrict__ extra,
                                                    const float* __restrict__ w_so, const float* __restrict__ b_so,
                                                    const float* __restrict__ w_aw, const float* __restrict__ b_aw,
                                                    float* __restrict__ xa) {
    __shared__ float ws_[16 * CIN];
    int tile = blockIdx.x;
    int nt   = blockIdx.y;
    int z    = blockIdx.z;
    int net = z >> 2, ocg = z & 3;
    const float* wsel = net ? w_aw : w_so;
    const float* bsel = net ? b_aw : b_so;
    for (int i = threadIdx.x; i < 16 * CIN; i += 256)
        ws_[i] = wsel[(size_t)(ocg * 16) * CIN + i];
    __syncthreads();
    int pix = tile * 256 + threadIdx.x;
    float acc[16];
#pragma unroll
    for (int o = 0; o < 16; o++) acc[o] = bsel[ocg * 16 + o];
    const float* in = extra + (size_t)nt * CIN * NPIX + pix;
    for (int ci = 0; ci < CIN; ci++) {
        float v = in[(size_t)ci * NPIX];
#pragma unroll
        for (int o = 0; o < 16; o++) acc[o] = fmaf(ws_[o * CIN + ci], v, acc[o]);
    }
    float* op = xa + (((size_t)net * NT + nt) * 64 + ocg * 16) * NPIX + pix;
#pragma unroll
    for (int o = 0; o < 16; o++) op[(size_t)o * NPIX] = leaky_f(acc[o]);
}

// ---- K4 (R8): 3x3 conv 64->64 pad1 + leaky, register-tile fp32 ----
__global__ __launch_bounds__(256) void k_conv3x3(const float* __restrict__ xin,
                                                 const float* __restrict__ wT,    // [net][64ic][9][64oc]
                                                 const float* __restrict__ b_so, const float* __restrict__ b_aw,
                                                 float* __restrict__ xout) {
    __shared__ float At[16][6][24];
    __shared__ float Bt[16][9][64];
    int tid = threadIdx.x;
    int txq = tid & 3, tyq = (tid >> 2) & 3, ocg = tid >> 4;
    int st = blockIdx.x;
    int x0 = (st % 3) * 16, y0 = (st / 3) * 4;
    int nt = blockIdx.y, net = blockIdx.z;
    const float* in  = xin + ((size_t)net * NT + nt) * 64 * NPIX;
    const float* wTn = wT + (size_t)net * 36864;
    const float* bsel = net ? b_aw : b_so;

    float acc[4][4];   // [oc][px]
#pragma unroll
    for (int o = 0; o < 4; o++) {
        float bv = bsel[ocg * 4 + o];
#pragma unroll
        for (int p = 0; p < 4; p++) acc[o][p] = bv;
    }

    for (int c0 = 0; c0 < 64; c0 += 16) {
        __syncthreads();
        for (int i = tid; i < 1728; i += 256) {
            int ic = i / 108, r = i % 108;
            int ry = r / 18, rx = r % 18;
            int gy = y0 + ry - 1, gx = x0 + rx - 1;
            float v = 0.f;
            if (gy >= 0 && gy < HS && gx >= 0 && gx < WSB)
                v = in[(size_t)(c0 + ic) * NPIX + gy * WSB + gx];
            At[ic][ry][rx] = v;
        }
        {
            const float* src = wTn + (size_t)c0 * 576;
            float* dst = &Bt[0][0][0];
            for (int i = tid; i < 9216; i += 256) dst[i] = src[i];
        }
        __syncthreads();
#pragma unroll 2
        for (int ic = 0; ic < 16; ic++) {
#pragma unroll
            for (int dy = 0; dy < 3; dy++) {
                f32x4 a0 = *reinterpret_cast<const f32x4*>(&At[ic][tyq + dy][4 * txq]);
                f32x4 a1 = *reinterpret_cast<const f32x4*>(&At[ic][tyq + dy][4 * txq + 4]);
#pragma unroll
                for (int dx = 0; dx < 3; dx++) {
                    f32x4 bv = *reinterpret_cast<const f32x4*>(&Bt[ic][dy * 3 + dx][4 * ocg]);
#pragma unroll
                    for (int p = 0; p < 4; p++) {
                        float av = (dx + p < 4) ? a0[dx + p] : a1[dx + p - 4];
#pragma unroll
                        for (int o = 0; o < 4; o++)
                            acc[o][p] = fmaf(bv[o], av, acc[o][p]);
                    }
                }
            }
        }
    }

    int py = y0 + tyq, pxb = x0 + 4 * txq;
#pragma unroll
    for (int o = 0; o < 4; o++) {
        f32x4 res;
#pragma unroll
        for (int p = 0; p < 4; p++) res[p] = leaky_f(acc[o][p]);
        float* op = xout + (((size_t)net * NT + nt) * 64 + ocg * 4 + o) * NPIX + py * WSB + pxb;
        *reinterpret_cast<f32x4*>(op) = res;
    }
}

// ---- K5: final 1x1 convs ----
__global__ __launch_bounds__(256) void k_conv1x1_l3(const float* __restrict__ xin,
                                                    const float* __restrict__ w_so, const float* __restrict__ b_so,
                                                    const float* __restrict__ w_aw, const float* __restrict__ b_aw,
                                                    float* __restrict__ offs, float* __restrict__ araw) {
    int pix = blockIdx.x * 256 + threadIdx.x;
    int nt = blockIdx.y;
    int net = blockIdx.z;
    const float* in = xin + ((size_t)net * NT + nt) * 64 * NPIX + pix;
    if (net == 0) {
        float acc[32];
#pragma unroll
        for (int o = 0; o < 32; o++) acc[o] = b_so[o];
        for (int ci = 0; ci < 64; ci++) {
            float v = in[(size_t)ci * NPIX];
#pragma unroll
            for (int o = 0; o < 32; o++) acc[o] = fmaf(w_so[o * 64 + ci], v, acc[o]);
        }
#pragma unroll
        for (int o = 0; o < 32; o++) offs[((size_t)nt * 32 + o) * NPIX + pix] = acc[o];
    } else {
        float acc[16];
#pragma unroll
        for (int o = 0; o < 16; o++) acc[o] = b_aw[o];
        for (int ci = 0; ci < 64; ci++) {
            float v = in[(size_t)ci * NPIX];
#pragma unroll
            for (int o = 0; o < 16; o++) acc[o] = fmaf(w_aw[o * 64 + ci], v, acc[o]);
        }
#pragma unroll
        for (int o = 0; o < 16; o++) araw[((size_t)nt * 16 + o) * NPIX + pix] = acc[o];
    }
}

// ---- K6: softmax over 12 (t,p) + sample-index precompute ----
__global__ __launch_bounds__(256) void k_softmax_idx(const float* __restrict__ araw,
                                                     const float* __restrict__ offs,
                                                     const float* __restrict__ flow,
                                                     float* __restrict__ attnw, int* __restrict__ sidx) {
    int idx = blockIdx.x * 256 + threadIdx.x;
    if (idx >= 2 * 4 * NPIX) return;
    int pix  = idx % NPIX;
    int head = (idx / NPIX) & 3;
    int n    = idx / (NPIX * 4);
    int x = pix % WSB, y = pix / WSB;
    float a[12];
#pragma unroll
    for (int t = 0; t < 3; t++)
#pragma unroll
        for (int p = 0; p < 4; p++)
            a[t * 4 + p] = araw[(((size_t)(n * 3 + t)) * 16 + head * 4 + p) * NPIX + pix];
    float mx = a[0];
#pragma unroll
    for (int k = 1; k < 12; k++) mx = fmaxf(mx, a[k]);
    float ssum = 0.f;
#pragma unroll
    for (int k = 0; k < 12; k++) { a[k] = expf(a[k] - mx); ssum += a[k]; }
    float inv = 1.0f / ssum;
#pragma unroll
    for (int t = 0; t < 3; t++) {
        int nt = n * 3 + t;
        float fx = flow[((size_t)nt * 2 + 0) * NPIX + pix];
        float fy = flow[((size_t)nt * 2 + 1) * NPIX + pix];
        float locx = fx + (float)x;
        float locy = fy + (float)y;
#pragma unroll
        for (int p = 0; p < 4; p++) {
            int hp = head * 4 + p;
            float gx_ = locx + offs[(((size_t)nt) * 32 + hp * 2 + 0) * NPIX + pix];
            float gy_ = locy + offs[(((size_t)nt) * 32 + hp * 2 + 1) * NPIX + pix];
            float ngx = 2.0f * gx_ / 48.0f - 1.0f;
            float ngy = 2.0f * gy_ / 48.0f - 1.0f;
            float rx = rintf(((ngx + 1.0f) * 0.5f) * 47.0f);
            float ry = rintf(((ngy + 1.0f) * 0.5f) * 47.0f);
            bool valid = (rx >= 0.f) && (rx <= 47.f) && (ry >= 0.f) && (ry <= 47.f);
            int sx = (int)fminf(fmaxf(rx, 0.f), 47.f);
            int sy = (int)fminf(fmaxf(ry, 0.f), 47.f);
            int k = t * 4 + p;
            attnw[(size_t)idx * 12 + k] = valid ? a[k] * inv : 0.f;
            sidx[(size_t)idx * 12 + k]  = sy * WSB + sx;
        }
    }
}

// ---- K6.5 (fallback): per-n transpose sp -> spT[t][pix][2048] bf16 ----
__global__ __launch_bounds__(256) void k_transpose(const float* __restrict__ sp,
                                                   u16* __restrict__ spT, int n) {
    __shared__ float tile[64][65];
    int tid = threadIdx.x;
    int pix0 = blockIdx.x * 64;
    int ch0  = blockIdx.y * 64;
    int tl   = blockIdx.z;
    int nt = n * 3 + tl;
    const float* base = sp + ((size_t)nt * 2048 + ch0) * NPIX + pix0;
#pragma unroll
    for (int k = 0; k < 16; k++) {
        int row = k * 4 + (tid >> 6);
        int col = tid & 63;
        tile[row][col] = base[(size_t)row * NPIX + col];
    }
    __syncthreads();
#pragma unroll
    for (int k = 0; k < 2; k++) {
        int task = k * 256 + tid;
        int pl = task >> 3;
        int c0 = (task & 7) * 8;
        u16 pk[8];
#pragma unroll
        for (int j = 0; j < 8; j++) pk[j] = f2bf(tile[c0 + j][pl]);
        *reinterpret_cast<int4*>(spT + ((size_t)tl * NPIX + pix0 + pl) * 2048 + ch0 + c0) =
            *reinterpret_cast<const int4*>(pk);
    }
}

// ---- K7 (fallback): coalesced 12-term gather, explicit n ----
__global__ __launch_bounds__(256) void k_gather2(const u16* __restrict__ spT,
                                                 const float* __restrict__ attnw,
                                                 const int* __restrict__ sidx,
                                                 u16* __restrict__ outimg, int n) {
    __shared__ u16 sArr[2048 + 128];
    int tid = threadIdx.x;
    int pix = blockIdx.x;
    int y = pix / WSB, x = pix % WSB;
    int h = tid >> 6;
    int lane = tid & 63;
    size_t ab = ((size_t)(n * 4 + h) * NPIX + pix) * 12;
    float acc[8] = {};
#pragma unroll
    for (int t = 0; t < 3; t++) {
#pragma unroll
        for (int p = 0; p < 4; p++) {
            int k = t * 4 + p;
            float w = attnw[ab + k];
            int idx = sidx[ab + k];
            bf16x8 v = *reinterpret_cast<const bf16x8*>(
                spT + ((size_t)t * NPIX + idx) * 2048 + h * 512 + lane * 8);
#pragma unroll
            for (int j = 0; j < 8; j++)
                acc[j] = fmaf(w, bf2f((u16)v[j]), acc[j]);
        }
    }
    int c0 = h * 512 + lane * 8;
    int si = c0 + (c0 >> 4);
    u16 pk[8];
#pragma unroll
    for (int j = 0; j < 8; j++) pk[j] = f2bf(acc[j]);
    *reinterpret_cast<int4*>(&sArr[si]) = *reinterpret_cast<const int4*>(pk);
    __syncthreads();
    int opix = tid >> 4;
    int oc0 = (tid & 15) * 8;
    u16 ov[8];
#pragma unroll
    for (int j = 0; j < 8; j++) {
        int oc = oc0 + j;
        int ch = (oc >> 5) * 512 + (oc & 31) * 16 + opix;
        ov[j] = sArr[ch + (ch >> 4)];
    }
    int hq = y * 4 + (opix >> 2);
    int wq = x * 4 + (opix & 3);
    *reinterpret_cast<int4*>(outimg + (((size_t)(n * HH + hq) * WW + wq) << 7) + oc0) =
        *reinterpret_cast<const int4*>(ov);
}

// ---- K7b (big): both n in one launch, grid (NPIX, 2) ----
__global__ __launch_bounds__(256) void k_gather2b(const u16* __restrict__ spT2,
                                                  const float* __restrict__ attnw,
                                                  const int* __restrict__ sidx,
                                                  u16* __restrict__ outimg) {
    __shared__ u16 sArr[2048 + 128];
    int tid = threadIdx.x;
    int pix = blockIdx.x;
    int n   = blockIdx.y;
    const u16* spT = spT2 + (size_t)n * 3 * NPIX * 2048;
    int y = pix / WSB, x = pix % WSB;
    int h = tid >> 6;
    int lane = tid & 63;
    size_t ab = ((size_t)(n * 4 + h) * NPIX + pix) * 12;
    float acc[8] = {};
#pragma unroll
    for (int t = 0; t < 3; t++) {
#pragma unroll
        for (int p = 0; p < 4; p++) {
            int k = t * 4 + p;
            float w = attnw[ab + k];
            int idx = sidx[ab + k];
            bf16x8 v = *reinterpret_cast<const bf16x8*>(
                spT + ((size_t)t * NPIX + idx) * 2048 + h * 512 + lane * 8);
#pragma unroll
            for (int j = 0; j < 8; j++)
                acc[j] = fmaf(w, bf2f((u16)v[j]), acc[j]);
        }
    }
    int c0 = h * 512 + lane * 8;
    int si = c0 + (c0 >> 4);
    u16 pk[8];
#pragma unroll
    for (int j = 0; j < 8; j++) pk[j] = f2bf(acc[j]);
    *reinterpret_cast<int4*>(&sArr[si]) = *reinterpret_cast<const int4*>(pk);
    __syncthreads();
    int opix = tid >> 4;
    int oc0 = (tid & 15) * 8;
    u16 ov[8];
#pragma unroll
    for (int j = 0; j < 8; j++) {
        int oc = oc0 + j;
        int ch = (oc >> 5) * 512 + (oc & 31) * 16 + opix;
        ov[j] = sArr[ch + (ch >> 4)];
    }
    int hq = y * 4 + (opix >> 2);
    int wq = x * 4 + (opix & 3);
    *reinterpret_cast<int4*>(outimg + (((size_t)(n * HH + hq) * WW + wq) << 7) + oc0) =
        *reinterpret_cast<const int4*>(ov);
}

// ---- K8 (R16+swz): fusion 3x3 conv, oc-split MFMA implicit GEMM ----
// grid (24, 24, 2): x = pxtile*2 + ocq (twin ocq blocks dispatch adjacent ->
// second halo read L2-hits), y = pytile, z = nb. Same math as R8/R13 form.
__global__ __launch_bounds__(256, 3) void k_fusion_mfma(const u16* __restrict__ img,   // bf16 NHWC
                                                        const u16* __restrict__ wbf,   // bf16 slab layout
                                                        const float* __restrict__ bias,
                                                        const float* __restrict__ anchor,
                                                        float* __restrict__ out) {
    __shared__ __align__(16) u16 lds_in[180 * 128];   // halo 10x18 x 128ic, swizzled

    const int tid = threadIdx.x;
    const int px0 = (blockIdx.x >> 1) * 16;
    const int ocq = blockIdx.x & 1;
    const int py0 = blockIdx.y * 8;
    const int nb  = blockIdx.z;
    const int lane = tid & 63;
    const int w = tid >> 6;
    const int r = lane & 15, g = lane >> 4;

    char* lin_b = reinterpret_cast<char*>(lds_in);

    for (int i = tid; i < 180 * 16; i += 256) {
        int p = i >> 4, c16 = i & 15;
        int hy = p / 18, hx = p % 18;
        int gy = py0 + hy - 1, gx = px0 + hx - 1;
        int4 v = make_int4(0, 0, 0, 0);
        if (gy >= 0 && gy < HH && gx >= 0 && gx < WW)
            v = *reinterpret_cast<const int4*>(img + (((size_t)(nb * HH + gy) * WW + gx) << 7) + (c16 << 3));
        *reinterpret_cast<int4*>(lin_b + p * 256 + (((c16 ^ (p & 7)) << 4))) = v;
    }

    const u16* wb = wbf + (size_t)(ocq * 64 + r) * 32 + g * 8;

    f32x4 acc[2][4] = {};
    bf16x8 b[2][4];
#pragma unroll
    for (int n = 0; n < 4; n++)
        b[0][n] = *reinterpret_cast<const bf16x8*>(wb + (size_t)n * 512);

    __syncthreads();

#pragma unroll
    for (int ph = 0; ph < 36; ph++) {
        const int d = ph >> 2, kc = ph & 3;
        const int dy = d / 3, dx = d % 3;
        if (ph < 35) {
#pragma unroll
            for (int n = 0; n < 4; n++)
                b[(ph + 1) & 1][n] = *reinterpret_cast<const bf16x8*>(
                    wb + (size_t)(ph + 1) * 4096 + (size_t)n * 512);
        }
        const int c16 = kc * 4 + g;
        bf16x8 a[2];
#pragma unroll
        for (int m = 0; m < 2; m++) {
            int hp = (2 * w + m + dy) * 18 + (r + dx);
            a[m] = *reinterpret_cast<const bf16x8*>(lin_b + hp * 256 + (((c16 ^ (hp & 7)) << 4)));
        }
#pragma unroll
        for (int m = 0; m < 2; m++)
#pragma unroll
            for (int n = 0; n < 4; n++)
                acc[m][n] = __builtin_amdgcn_mfma_f32_16x16x32_bf16(a[m], b[ph & 1][n], acc[m][n], 0, 0, 0);
    }

    float bs[4];
#pragma unroll
    for (int n = 0; n < 4; n++) bs[n] = bias[ocq * 64 + n * 16 + r];
#pragma unroll
    for (int m = 0; m < 2; m++) {
        int gy = py0 + 2 * w + m;
#pragma unroll
        for (int n = 0; n < 4; n++) {
            int oc = ocq * 64 + n * 16 + r;
            size_t oa = ((size_t)(nb * CCH + oc)) * (HH * WW) + (size_t)gy * WW + px0 + g * 4;
            f32x4 av = *reinterpret_cast<const f32x4*>(anchor + oa);
            f32x4 res;
#pragma unroll
            for (int q = 0; q < 4; q++) res[q] = acc[m][n][q] + bs[n] + av[q];
            *reinterpret_cast<f32x4*>(out + oa) = res;
        }
    }
}

extern "C" void kernel_launch(void* const* d_in, const int* in_sizes, int n_in,
                              void* d_out, int out_size, void* d_ws, size_t ws_size,
                              hipStream_t stream) {
    (void)in_sizes; (void)n_in; (void)out_size;
    const float* anchor = (const float*)d_in[1];
    const float* sp     = (const float*)d_in[2];
    const float* flow   = (const float*)d_in[3];
    const float* so_w0 = (const float*)d_in[4];  const float* so_b0 = (const float*)d_in[5];
    const float* so_w1 = (const float*)d_in[6];  const float* so_b1 = (const float*)d_in[7];
    const float* so_w2 = (const float*)d_in[8];  const float* so_b2 = (const float*)d_in[9];
    const float* so_w3 = (const float*)d_in[10]; const float* so_b3 = (const float*)d_in[11];
    const float* aw_w0 = (const float*)d_in[12]; const float* aw_b0 = (const float*)d_in[13];
    const float* aw_w1 = (const float*)d_in[14]; const float* aw_b1 = (const float*)d_in[15];
    const float* aw_w2 = (const float*)d_in[16]; const float* aw_b2 = (const float*)d_in[17];
    const float* aw_w3 = (const float*)d_in[18]; const float* aw_b3 = (const float*)d_in[19];
    const float* fw    = (const float*)d_in[20]; const float* fb    = (const float*)d_in[21];

    float* ws   = (float*)d_ws;
    float* outp = (float*)d_out;
    const bool big = ws_size >= TOTAL2_F32 * 4ull;

    float* extra; float* xa; float* xb; float* offs; float* araw; float* wT;
    float* attnw; int* sidx; u16* wbf; u16* outimg;

    if (big) {
        extra = ws + EXTRA2_OFF;  xa = ws + XA2_OFF;    xb = ws + XB2_OFF;
        offs  = ws + OFFS2_OFF;   araw = ws + ARAW2_OFF; wT = ws + WT2_OFF;
        attnw = ws + ATTNW2_OFF;  sidx = (int*)(ws + SIDX2_OFF);
        wbf   = (u16*)(ws + WBF2_OFF);  outimg = (u16*)(ws + OUTIMG2_OFF);
    } else {
        extra = ws + EXTRA_OFF;   xa = ws + XA_OFF;     xb = ws + XB_OFF;
        offs  = ws + OFFS_OFF;    araw = ws + ARAW_OFF;  wT = ws + WT_OFF;
        attnw = ws + ATTNW_OFF;   sidx = (int*)(ws + SIDX_OFF);
        wbf   = (u16*)(ws + WBF_OFF);   outimg = (u16*)(ws + OUTIMG_OFF);
    }

    k_wprep<<<dim3(576), 256, 0, stream>>>(fw, wbf);
    k_wprep2<<<dim3(576), 256, 0, stream>>>(so_w1, aw_w1, so_w2, aw_w2, wT);

    if (big) {
        u16* spT2 = (u16*)(ws + SPT2_OFF);
        k_spprep<<<dim3(36, 32, 6), 256, 0, stream>>>(sp, spT2, extra);
        k_extra_rest<<<dim3((NT * 130 * NPIX + 255) / 256), 256, 0, stream>>>(flow, extra);
        k_conv1x1_l0<<<dim3(9, 6, 8), 256, 0, stream>>>(extra, so_w0, so_b0, aw_w0, aw_b0, xa);
        k_conv3x3<<<dim3(36, 6, 2), 256, 0, stream>>>(xa, wT, so_b1, aw_b1, xb);
        k_conv3x3<<<dim3(36, 6, 2), 256, 0, stream>>>(xb, wT + 73728, so_b2, aw_b2, xa);
        k_conv1x1_l3<<<dim3(9, 6, 2), 256, 0, stream>>>(xa, so_w3, so_b3, aw_w3, aw_b3, offs, araw);
        k_softmax_idx<<<dim3((2 * 4 * NPIX + 255) / 256), 256, 0, stream>>>(araw, offs, flow, attnw, sidx);
        k_gather2b<<<dim3(NPIX, 2), 256, 0, stream>>>(spT2, attnw, sidx, outimg);
    } else {
        u16* spT = (u16*)(ws + SPT_OFF);
        k_avgpool<<<dim3((NT * CCH * NPIX + 255) / 256), 256, 0, stream>>>(sp, extra);
        k_extra_rest<<<dim3((NT * 130 * NPIX + 255) / 256), 256, 0, stream>>>(flow, extra);
        k_conv1x1_l0<<<dim3(9, 6, 8), 256, 0, stream>>>(extra, so_w0, so_b0, aw_w0, aw_b0, xa);
        k_conv3x3<<<dim3(36, 6, 2), 256, 0, stream>>>(xa, wT, so_b1, aw_b1, xb);
        k_conv3x3<<<dim3(36, 6, 2), 256, 0, stream>>>(xb, wT + 73728, so_b2, aw_b2, xa);
        k_conv1x1_l3<<<dim3(9, 6, 2), 256, 0, stream>>>(xa, so_w3, so_b3, aw_w3, aw_b3, offs, araw);
        k_softmax_idx<<<dim3((2 * 4 * NPIX + 255) / 256), 256, 0, stream>>>(araw, offs, flow, attnw, sidx);
        for (int n = 0; n < 2; n++) {
            k_transpose<<<dim3(36, 32, 3), 256, 0, stream>>>(sp, spT, n);
            k_gather2<<<dim3(NPIX), 256, 0, stream>>>(spT, attnw, sidx, outimg, n);
        }
    }
    k_fusion_mfma<<<dim3(24, 24, 2), 256, 0, stream>>>(outimg, wbf, fb, anchor, outp);
}